// Round 10
// baseline (165.034 us; speedup 1.0000x reference)
//
#include <hip/hip_runtime.h>
#include <hip/hip_fp16.h>
#include <cstdint>

// Problem constants
#define BB 8
#define NN 256
#define NC 5
#define NH 8
#define DIM 512
#define HD 64

typedef _Float16 half_t;
typedef _Float16 h8 __attribute__((ext_vector_type(8)));
typedef _Float16 h4 __attribute__((ext_vector_type(4)));
typedef float f4 __attribute__((ext_vector_type(4)));
typedef uint32_t u4v __attribute__((ext_vector_type(4)));

__device__ __forceinline__ f4 mfma16(h8 a, h8 b, f4 c) {
  return __builtin_amdgcn_mfma_f32_16x16x32_f16(a, b, c, 0, 0, 0);
}

static __device__ const h8 HZERO = {(_Float16)0, (_Float16)0, (_Float16)0, (_Float16)0,
                                    (_Float16)0, (_Float16)0, (_Float16)0, (_Float16)0};

__device__ __forceinline__ h8 relu_pos_h8(h8 x) {
#if __has_builtin(__builtin_elementwise_max)
  return __builtin_elementwise_max(x, HZERO);
#else
  u4v u = __builtin_bit_cast(u4v, x);
  const u4v k1 = {0x00010001u, 0x00010001u, 0x00010001u, 0x00010001u};
  u4v s = (u >> 15) & k1;
  u4v m = (s << 16) - s;
  u = u & ~m;
  return __builtin_bit_cast(h8, u);
#endif
}

__device__ __forceinline__ h8 relu_neg_h8(h8 x) {
#if __has_builtin(__builtin_elementwise_max)
  return __builtin_elementwise_max(-x, HZERO);
#else
  u4v u = __builtin_bit_cast(u4v, x);
  const u4v k1 = {0x00010001u, 0x00010001u, 0x00010001u, 0x00010001u};
  const u4v ks = {0x80008000u, 0x80008000u, 0x80008000u, 0x80008000u};
  u4v s = (u >> 15) & k1;
  u4v m = (s << 16) - s;
  u = (u ^ ks) & m;
  return __builtin_bit_cast(h8, u);
#endif
}

// Raw barrier: waits LDS only, does NOT drain vmcnt (global stores stay in flight).
__device__ __forceinline__ void barrier_lds() {
  __builtin_amdgcn_sched_barrier(0);
  asm volatile("s_waitcnt lgkmcnt(0)" ::: "memory");
  __builtin_amdgcn_s_barrier();
  asm volatile("" ::: "memory");
  __builtin_amdgcn_sched_barrier(0);
}

// ---------------------------------------------------------------------------
// K0: convert x, anchors, qk_w, v_w, proj_w to fp16.
// ---------------------------------------------------------------------------
__global__ __launch_bounds__(256) void cvt_all(const float* __restrict__ x,
                                               const float* __restrict__ anchors,
                                               const float* __restrict__ qk_w,
                                               const float* __restrict__ v_w,
                                               const float* __restrict__ proj_w,
                                               half_t* __restrict__ x_h,
                                               half_t* __restrict__ anc_h,
                                               half_t* __restrict__ qk_h,
                                               half_t* __restrict__ v_wh,
                                               half_t* __restrict__ pw_h) {
  int i = blockIdx.x * 256 + threadIdx.x;
  const float* src;
  half_t* dst;
  int off;
  if (i < 262144)      { src = x;       dst = x_h;   off = i; }
  else if (i < 425984) { src = anchors; dst = anc_h; off = i - 262144; }
  else if (i < 491520) { src = qk_w;    dst = qk_h;  off = i - 425984; }
  else if (i < 557056) { src = v_w;     dst = v_wh;  off = i - 491520; }
  else                 { src = proj_w;  dst = pw_h;  off = i - 557056; }
  float4 v = ((const float4*)src)[off];
  h4 o;
  o[0] = (_Float16)v.x; o[1] = (_Float16)v.y; o[2] = (_Float16)v.z; o[3] = (_Float16)v.w;
  ((h4*)dst)[off] = o;
}

// ---------------------------------------------------------------------------
// K1: all three projections (pure fp16 operands).
// ---------------------------------------------------------------------------
__global__ __launch_bounds__(256) void proj_all(const half_t* __restrict__ x_h,
                                                const half_t* __restrict__ anc_h,
                                                const half_t* __restrict__ qk_h,
                                                const half_t* __restrict__ v_wh,
                                                half_t* __restrict__ q_h,
                                                half_t* __restrict__ k_h,
                                                half_t* __restrict__ vT) {
  const int bx = blockIdx.x, by = blockIdx.y;
  const int tid = threadIdx.x;
  const int w = tid >> 6, lane = tid & 63;
  const int lr = lane & 15, lk = (lane >> 4) * 8, lg = lane >> 4;

  const half_t* A;
  const half_t* W;
  int mode, rt0;
  if (bx < 32)      { A = x_h;   W = qk_h; mode = 0; rt0 = bx * 64; }
  else if (bx < 52) { A = anc_h; W = qk_h; mode = 1; rt0 = (bx - 32) * 64; }
  else              { A = x_h;   W = v_wh; mode = 2; rt0 = (bx - 52) * 64; }

  const int row0 = rt0 + w * 16;
  const int col0 = by * 64;
  const f4 fz = {0.f, 0.f, 0.f, 0.f};
  f4 acc[4] = {fz, fz, fz, fz};
  const half_t* arow = A + (size_t)(row0 + lr) * DIM;

  if (mode != 2) {
    for (int k0 = 0; k0 < DIM; k0 += 32) {
      h8 a = *(const h8*)(arow + k0 + lk);
#pragma unroll
      for (int ct = 0; ct < 4; ++ct) {
        h8 b = *(const h8*)(W + (size_t)(col0 + ct * 16 + lr) * DIM + k0 + lk);
        acc[ct] = mfma16(a, b, acc[ct]);
      }
    }
    half_t* out = (mode == 0) ? q_h : k_h;
#pragma unroll
    for (int ct = 0; ct < 4; ++ct) {
      int col = col0 + ct * 16 + lr;
#pragma unroll
      for (int r = 0; r < 4; ++r) {
        int row = row0 + lg * 4 + r;
        out[(size_t)row * DIM + col] = (half_t)acc[ct][r];
      }
    }
  } else {
    for (int k0 = 0; k0 < DIM; k0 += 32) {
      h8 a = *(const h8*)(arow + k0 + lk);
#pragma unroll
      for (int ct = 0; ct < 4; ++ct) {
        h8 b = *(const h8*)(W + (size_t)(col0 + ct * 16 + lr) * DIM + k0 + lk);
        acc[ct] = mfma16(b, a, acc[ct]);
      }
    }
    const int xrow = row0 + lr;
#pragma unroll
    for (int ct = 0; ct < 4; ++ct) {
#pragma unroll
      for (int r = 0; r < 4; ++r) {
        int col = col0 + ct * 16 + lg * 4 + r;  // = h*64 + d
        vT[(size_t)col * (BB * NN) + xrow] = (half_t)acc[ct][r];
      }
    }
  }
}

// ---------------------------------------------------------------------------
// K2a: a0 = 0.125 * q @ k^T as a pure streaming GEMM.
// 1280 blocks (task x quarter), 256 thr, 32KB LDS -> 4+ blocks/CU.
// Writes the mandatory 84 MB fp32 a0 at HBM streaming rate.
// ---------------------------------------------------------------------------
__global__ __launch_bounds__(256, 4) void a0_gemm(const half_t* __restrict__ q_h,
                                                  const half_t* __restrict__ k_h,
                                                  float* __restrict__ a0_base) {
  __shared__ half_t kst[256 * 64];  // swizzled, 32 KB
  const int bid = blockIdx.x;       // 1280
  const int task = bid >> 2, quarter = bid & 3;
  const int b = task / 40;
  const int rem = task % 40;
  const int c = rem / 8;
  const int h = rem & 7;

  const int tid = threadIdx.x;
  const int w = tid >> 6, lane = tid & 63;
  const int lr = lane & 15, lk = (lane >> 4) * 8, lg = lane >> 4;

  const half_t* qb = q_h + (size_t)(b * NN) * DIM + h * HD;
  const half_t* kb = k_h + (size_t)(c * NN) * DIM + h * HD;
  float* a0out = a0_base + (size_t)((b * NC + c) * NH + h) * (NN * NN);

  // stage full k tile [256][64]
#pragma unroll
  for (int pass = 0; pass < 8; ++pass) {
    int slot = pass * 256 + tid;
    int row = slot >> 3, k8 = (slot & 7) * 8;
    *(h8*)(kst + ((row * 64 + k8) ^ ((row & 7) << 3))) =
        *(const h8*)(kb + (size_t)row * DIM + k8);
  }
  __syncthreads();

  const int n0 = quarter * 64 + w * 16;
  h8 qf0 = *(const h8*)(qb + (size_t)(n0 + lr) * DIM + lk);
  h8 qf1 = *(const h8*)(qb + (size_t)(n0 + lr) * DIM + 32 + lk);
  const f4 fz = {0.f, 0.f, 0.f, 0.f};
  const int na = n0 + lr;
#pragma unroll
  for (int mt = 0; mt < 16; ++mt) {
    const int krow = mt * 16 + lr;
    h8 kf0 = *(const h8*)(kst + ((krow * 64 + lk) ^ ((krow & 7) << 3)));
    h8 kf1 = *(const h8*)(kst + ((krow * 64 + 32 + lk) ^ ((krow & 7) << 3)));
    f4 acc = mfma16(kf0, qf0, fz);
    acc = mfma16(kf1, qf1, acc);
#pragma unroll
    for (int r = 0; r < 4; ++r) acc[r] *= 0.125f;
    // D: col = n (lane&15), row = m (lg*4+r consecutive) -> coalesced f4
    *(f4*)(a0out + (size_t)na * NN + mt * 16 + lg * 4) = acc;
  }
}

// ---------------------------------------------------------------------------
// K2b: per (b,c,h) task: stage a0 (fp32 from d_out, L3-hot) -> fp16 swz LDS,
// S = relu(-a0) @ relu(a0)^T (square wave tiles [32n][128m']), column softmax
// (2 LDS passes), PV with v fragments straight from L2-hot vT, partial U4.
// 320 blocks x 1024 thr; LDS 146.5 KB -> 1 blk/CU, 4 waves/SIMD. 3 barriers.
// ---------------------------------------------------------------------------
__global__ __launch_bounds__(1024, 4) void attn_sm(const float* __restrict__ a0_base,
                                                   const half_t* __restrict__ vT,
                                                   const float* __restrict__ weights,
                                                   half_t* __restrict__ U4) {
  extern __shared__ char smem[];
  half_t* a0s = (half_t*)smem;                    // [256][256] swz, 131072 B
  half_t* pbuf = (half_t*)(smem + 32768);         // overlay: 16 x [32][42] (a0s dead)
  float2* scr = (float2*)(smem + 131072);         // [8 sg][256 m'], 16384 B
  float2* scr2 = (float2*)(smem + 147456);        // [256 m'] (gm,sg), 2048 B

  const int id = blockIdx.x;  // 320
  const int b = id / 40;
  const int rem = id % 40;
  const int c = rem / 8;
  const int h = rem & 7;

  const int tid = threadIdx.x;
  const int w = tid >> 6, lane = tid & 63;
  const int lr = lane & 15, lk = (lane >> 4) * 8, lg = lane >> 4;
  const int sg = w & 7, cg = w >> 3;

  const float* a0f = a0_base + (size_t)((b * NC + c) * NH + h) * (NN * NN);
  const half_t* vTb = vT + (size_t)(h * HD) * (BB * NN) + b * NN;
  const float wgt = weights[(b * NH + h) * NC + c];

  const f4 fz = {0.f, 0.f, 0.f, 0.f};

  // ---- stage a0 fp32 -> fp16 swizzled LDS (8 h8-slots per thread) ----
#pragma unroll
  for (int pass = 0; pass < 8; ++pass) {
    int slot = pass * 1024 + tid;  // 8192 h8-slots
    int n = slot >> 5, m8 = (slot & 31) * 8;
    const float* p = a0f + (size_t)n * NN + m8;
    f4 va = *(const f4*)p;
    f4 vb = *(const f4*)(p + 4);
    h8 hv;
#pragma unroll
    for (int r = 0; r < 4; ++r) {
      hv[r] = (_Float16)va[r];
      hv[4 + r] = (_Float16)vb[r];
    }
    *(h8*)(a0s + ((n * NN + m8) ^ ((n & 7) << 3))) = hv;
  }
  barrier_lds();  // A: a0s ready

  // ---- S = relu(-a0) @ relu(a0)^T, wave tile [32 n][128 m'] ----
  f4 sacc[8][2];
#pragma unroll
  for (int ct = 0; ct < 8; ++ct) {
    sacc[ct][0] = fz;
    sacc[ct][1] = fz;
  }
#pragma unroll
  for (int kc = 0; kc < 8; ++kc) {
    const int rl0 = sg * 32 + lr, rl1 = sg * 32 + 16 + lr;
    h8 La0 = relu_neg_h8(*(const h8*)(a0s + ((rl0 * NN + kc * 32 + lk) ^ ((rl0 & 7) << 3))));
    h8 La1 = relu_neg_h8(*(const h8*)(a0s + ((rl1 * NN + kc * 32 + lk) ^ ((rl1 & 7) << 3))));
#pragma unroll
    for (int ct = 0; ct < 8; ++ct) {
      const int rr = cg * 128 + ct * 16 + lr;
      h8 R = relu_pos_h8(*(const h8*)(a0s + ((rr * NN + kc * 32 + lk) ^ ((rr & 7) << 3))));
      sacc[ct][0] = mfma16(La0, R, sacc[ct][0]);
      sacc[ct][1] = mfma16(La1, R, sacc[ct][1]);
    }
  }

  // ---- softmax over n per m'-col: wave-local (max,sum), exp in place ----
  float mw[8];
#pragma unroll
  for (int ct = 0; ct < 8; ++ct) {
    float v = 0.f;  // S >= 0 always
#pragma unroll
    for (int rt = 0; rt < 2; ++rt)
#pragma unroll
      for (int r = 0; r < 4; ++r) v = fmaxf(v, sacc[ct][rt][r]);
    v = fmaxf(v, __shfl_xor(v, 16, 64));
    v = fmaxf(v, __shfl_xor(v, 32, 64));
    mw[ct] = v;
    float s = 0.f;
#pragma unroll
    for (int rt = 0; rt < 2; ++rt)
#pragma unroll
      for (int r = 0; r < 4; ++r) {
        float e = __expf(sacc[ct][rt][r] - v);
        sacc[ct][rt][r] = e;
        s += e;
      }
    s += __shfl_xor(s, 16, 64);
    s += __shfl_xor(s, 32, 64);
    if (lane < 16) {
      float2 t;
      t.x = v;
      t.y = s;
      scr[sg * 256 + cg * 128 + ct * 16 + lr] = t;
    }
  }
  barrier_lds();  // B: scr done, all a0s reads done

  // ---- combine across 8 sg (256 threads, one m'-column each) ----
  if (tid < 256) {
    float gm = 0.f;
#pragma unroll
    for (int ww = 0; ww < 8; ++ww) gm = fmaxf(gm, scr[ww * 256 + tid].x);
    float sg2 = 0.f;
#pragma unroll
    for (int ww = 0; ww < 8; ++ww) {
      float2 t = scr[ww * 256 + tid];
      sg2 += t.y * __expf(t.x - gm);
    }
    float2 r;
    r.x = gm;
    r.y = sg2;
    scr2[tid] = r;
  }
  barrier_lds();  // C: scr2 ready

  // fold fac into P
#pragma unroll
  for (int ct = 0; ct < 8; ++ct) {
    float2 t = scr2[cg * 128 + ct * 16 + lr];
    float fac = __expf(mw[ct] - t.x) * wgt / t.y;
#pragma unroll
    for (int rt = 0; rt < 2; ++rt)
#pragma unroll
      for (int r = 0; r < 4; ++r) sacc[ct][rt][r] *= fac;
  }

  // ---- PV per 32-m' panel: transpose-bounce P, v fragments from global ----
  half_t* pbw = pbuf + w * 1344;  // [32 m'][42 n-pad]
  f4 uacc[4][2];
#pragma unroll
  for (int dt = 0; dt < 4; ++dt) {
    uacc[dt][0] = fz;
    uacc[dt][1] = fz;
  }
#pragma unroll
  for (int p = 0; p < 4; ++p) {
#pragma unroll
    for (int ctl = 0; ctl < 2; ++ctl) {
      const int ct = p * 2 + ctl;
#pragma unroll
      for (int rt = 0; rt < 2; ++rt) {
        h4 hv;
#pragma unroll
        for (int r = 0; r < 4; ++r) hv[r] = (_Float16)sacc[ct][rt][r];
        *(h4*)(pbw + (ctl * 16 + lr) * 42 + rt * 16 + lg * 4) = hv;
      }
    }
    h8 pf0, pf1;
#pragma unroll
    for (int e = 0; e < 8; ++e) {
      pf0[e] = pbw[(lg * 8 + e) * 42 + lr];
      pf1[e] = pbw[(lg * 8 + e) * 42 + 16 + lr];
    }
#pragma unroll
    for (int dt = 0; dt < 4; ++dt) {
      // v fragment straight from global vT (L2-hot, 32KB per (b,h))
      h8 vf = *(const h8*)(vTb + (size_t)(dt * 16 + lr) * (BB * NN) + cg * 128 + p * 32 + lg * 8);
      uacc[dt][0] = mfma16(vf, pf0, uacc[dt][0]);
      uacc[dt][1] = mfma16(vf, pf1, uacc[dt][1]);
    }
  }

  // ---- store partial U4 (fp16): [n][d], slot = cg ----
  half_t* U4b = U4 + (size_t)(((b * NC + c) * NH + h) * 2 + cg) * (NN * HD);
#pragma unroll
  for (int dt = 0; dt < 4; ++dt)
#pragma unroll
    for (int nt = 0; nt < 2; ++nt) {
      int n = sg * 32 + nt * 16 + lr;
      h4 hv;
#pragma unroll
      for (int r = 0; r < 4; ++r) hv[r] = (_Float16)uacc[dt][nt][r];
      *(h4*)(U4b + (size_t)n * HD + dt * 16 + lg * 4) = hv;
    }
}

// ---------------------------------------------------------------------------
// K3: merged reduce + out-projection. 64 blocks, one per (b, hh) = 32 rows.
// Stage reduced A-tile (sum of 10 U4 partials) in LDS, then GEMM + bias.
// ---------------------------------------------------------------------------
__global__ __launch_bounds__(256) void out_projA(const half_t* __restrict__ U4,
                                                 const half_t* __restrict__ pw_h,
                                                 const float* __restrict__ pb,
                                                 float* __restrict__ out0) {
  __shared__ half_t Ast[32 * 520];  // [32 rows][512 k + 8 pad]
  const int bid = blockIdx.x;       // 64
  const int b = bid >> 3, hh = bid & 7;
  const int tid = threadIdx.x;

  // stage: thread (il = tid>>3, kk = tid&7) reduces 10 partial slices
  {
    const int il = tid >> 3, kk = tid & 7;
    const int n = (il << 3) | kk;
    const half_t* base = U4 + ((size_t)(b * NC * NH + hh) * 2) * (NN * HD) + (size_t)n * HD;
#pragma unroll
    for (int d0 = 0; d0 < HD; d0 += 8) {
      float a8[8] = {0.f, 0.f, 0.f, 0.f, 0.f, 0.f, 0.f, 0.f};
#pragma unroll
      for (int cc = 0; cc < NC; ++cc)
#pragma unroll
        for (int qq = 0; qq < 2; ++qq) {
          h8 u = *(const h8*)(base + (size_t)(cc * NH * 2 + qq) * (NN * HD) + d0);
#pragma unroll
          for (int j = 0; j < 8; ++j) a8[j] += (float)u[j];
        }
      h8 o;
#pragma unroll
      for (int j = 0; j < 8; ++j) o[j] = (_Float16)a8[j];
      *(h8*)(&Ast[il * 520 + kk * 64 + d0]) = o;
    }
  }
  __syncthreads();

  // GEMM: 4 waves x 128 cols each, 32 rows
  const int w = tid >> 6, lane = tid & 63;
  const int lr = lane & 15, lk = (lane >> 4) * 8, lg = lane >> 4;
  const int col0 = w * 128;
  const f4 fz = {0.f, 0.f, 0.f, 0.f};
  f4 acc[2][8];
#pragma unroll
  for (int rt = 0; rt < 2; ++rt)
#pragma unroll
    for (int ct = 0; ct < 8; ++ct) acc[rt][ct] = fz;

  for (int kc = 0; kc < 16; ++kc) {
    h8 a0f = *(const h8*)(&Ast[(lr)*520 + kc * 32 + lk]);
    h8 a1f = *(const h8*)(&Ast[(16 + lr) * 520 + kc * 32 + lk]);
#pragma unroll
    for (int ct = 0; ct < 8; ++ct) {
      h8 bf = *(const h8*)(pw_h + (size_t)(col0 + ct * 16 + lr) * DIM + kc * 32 + lk);
      acc[0][ct] = mfma16(a0f, bf, acc[0][ct]);
      acc[1][ct] = mfma16(a1f, bf, acc[1][ct]);
    }
  }

  const int row_base = b * NN + hh * 32;
#pragma unroll
  for (int ct = 0; ct < 8; ++ct) {
    int col = col0 + ct * 16 + lr;
    float bias = pb[col];
#pragma unroll
    for (int rt = 0; rt < 2; ++rt)
#pragma unroll
      for (int r = 0; r < 4; ++r) {
        int row = row_base + rt * 16 + lg * 4 + r;
        out0[(size_t)row * DIM + col] = acc[rt][ct][r] + bias;
      }
  }
}

// ---------------------------------------------------------------------------
extern "C" void kernel_launch(void* const* d_in, const int* in_sizes, int n_in,
                              void* d_out, int out_size, void* d_ws, size_t ws_size,
                              hipStream_t stream) {
  const float* x = (const float*)d_in[0];
  const float* anchors = (const float*)d_in[1];
  const float* weights = (const float*)d_in[2];
  const float* qk_w = (const float*)d_in[3];
  const float* v_w = (const float*)d_in[4];
  const float* proj_w = (const float*)d_in[5];
  const float* proj_b = (const float*)d_in[6];

  float* out0 = (float*)d_out;                       // [8,256,512]
  float* a0_out = out0 + (size_t)BB * NN * DIM;      // [8,5,8,256,256]

  char* ws = (char*)d_ws;
  const size_t MB = 1024 * 1024;
  // Region 0..20MB: fp16 staging (dead before attn_sm) then U4 overlay.
  half_t* x_h   = (half_t*)(ws);                  // 2 MB
  half_t* anc_h = (half_t*)(ws + 2 * MB);         // 1.25 MB
  half_t* qk_h  = (half_t*)(ws + 3407872);        // 0.5 MB
  half_t* v_wh  = (half_t*)(ws + 3932160);        // 0.5 MB
  half_t* U4    = (half_t*)(ws);                  // 20 MB (overlay)
  // Persistent region 20..26MB:
  half_t* pw_h = (half_t*)(ws + 20 * MB);           // 0.5 MB
  half_t* q_h  = (half_t*)(ws + 20 * MB + 524288);  // 2 MB
  half_t* k_h  = (half_t*)(ws + 22 * MB + 524288);  // 1.25 MB
  half_t* vT   = (half_t*)(ws + 24 * MB);           // 2 MB

  cvt_all<<<dim3(2432), 256, 0, stream>>>(x, anchors, qk_w, v_w, proj_w,
                                          x_h, anc_h, qk_h, v_wh, pw_h);

  proj_all<<<dim3(84, 8), 256, 0, stream>>>(x_h, anc_h, qk_h, v_wh, q_h, k_h, vT);

  a0_gemm<<<dim3(BB * NC * NH * 4), 256, 0, stream>>>(q_h, k_h, a0_out);

  const size_t lds_bytes = 131072 + 16384 + 2048;  // 149,504 B
  attn_sm<<<dim3(BB * NC * NH), 1024, lds_bytes, stream>>>(a0_out, vT, weights, U4);

  out_projA<<<dim3(64), 256, 0, stream>>>(U4, pw_h, proj_b, out0);

  (void)in_sizes; (void)n_in; (void)out_size; (void)ws_size;
}

// Round 11
// 150.878 us; speedup vs baseline: 1.0938x; 1.0938x over previous
//
#include <hip/hip_runtime.h>
#include <hip/hip_fp16.h>
#include <cstdint>

// Problem constants
#define BB 8
#define NN 256
#define NC 5
#define NH 8
#define DIM 512
#define HD 64

typedef _Float16 half_t;
typedef _Float16 h8 __attribute__((ext_vector_type(8)));
typedef _Float16 h4 __attribute__((ext_vector_type(4)));
typedef float f4 __attribute__((ext_vector_type(4)));
typedef uint32_t u4v __attribute__((ext_vector_type(4)));

__device__ __forceinline__ f4 mfma16(h8 a, h8 b, f4 c) {
  return __builtin_amdgcn_mfma_f32_16x16x32_f16(a, b, c, 0, 0, 0);
}

static __device__ const h8 HZERO = {(_Float16)0, (_Float16)0, (_Float16)0, (_Float16)0,
                                    (_Float16)0, (_Float16)0, (_Float16)0, (_Float16)0};

__device__ __forceinline__ h8 relu_pos_h8(h8 x) {
#if __has_builtin(__builtin_elementwise_max)
  return __builtin_elementwise_max(x, HZERO);
#else
  u4v u = __builtin_bit_cast(u4v, x);
  const u4v k1 = {0x00010001u, 0x00010001u, 0x00010001u, 0x00010001u};
  u4v s = (u >> 15) & k1;
  u4v m = (s << 16) - s;
  u = u & ~m;
  return __builtin_bit_cast(h8, u);
#endif
}

__device__ __forceinline__ h8 relu_neg_h8(h8 x) {
#if __has_builtin(__builtin_elementwise_max)
  return __builtin_elementwise_max(-x, HZERO);
#else
  u4v u = __builtin_bit_cast(u4v, x);
  const u4v k1 = {0x00010001u, 0x00010001u, 0x00010001u, 0x00010001u};
  const u4v ks = {0x80008000u, 0x80008000u, 0x80008000u, 0x80008000u};
  u4v s = (u >> 15) & k1;
  u4v m = (s << 16) - s;
  u = (u ^ ks) & m;
  return __builtin_bit_cast(h8, u);
#endif
}

// Raw barrier: waits LDS only, does NOT drain vmcnt (global stores stay in flight).
__device__ __forceinline__ void barrier_lds() {
  __builtin_amdgcn_sched_barrier(0);
  asm volatile("s_waitcnt lgkmcnt(0)" ::: "memory");
  __builtin_amdgcn_s_barrier();
  asm volatile("" ::: "memory");
  __builtin_amdgcn_sched_barrier(0);
}

// ---------------------------------------------------------------------------
// K0: convert x, anchors, qk_w, v_w, proj_w to fp16.
// ---------------------------------------------------------------------------
__global__ __launch_bounds__(256) void cvt_all(const float* __restrict__ x,
                                               const float* __restrict__ anchors,
                                               const float* __restrict__ qk_w,
                                               const float* __restrict__ v_w,
                                               const float* __restrict__ proj_w,
                                               half_t* __restrict__ x_h,
                                               half_t* __restrict__ anc_h,
                                               half_t* __restrict__ qk_h,
                                               half_t* __restrict__ v_wh,
                                               half_t* __restrict__ pw_h) {
  int i = blockIdx.x * 256 + threadIdx.x;
  const float* src;
  half_t* dst;
  int off;
  if (i < 262144)      { src = x;       dst = x_h;   off = i; }
  else if (i < 425984) { src = anchors; dst = anc_h; off = i - 262144; }
  else if (i < 491520) { src = qk_w;    dst = qk_h;  off = i - 425984; }
  else if (i < 557056) { src = v_w;     dst = v_wh;  off = i - 491520; }
  else                 { src = proj_w;  dst = pw_h;  off = i - 557056; }
  float4 v = ((const float4*)src)[off];
  h4 o;
  o[0] = (_Float16)v.x; o[1] = (_Float16)v.y; o[2] = (_Float16)v.z; o[3] = (_Float16)v.w;
  ((h4*)dst)[off] = o;
}

// ---------------------------------------------------------------------------
// K1: all three projections (pure fp16 operands).
// ---------------------------------------------------------------------------
__global__ __launch_bounds__(256) void proj_all(const half_t* __restrict__ x_h,
                                                const half_t* __restrict__ anc_h,
                                                const half_t* __restrict__ qk_h,
                                                const half_t* __restrict__ v_wh,
                                                half_t* __restrict__ q_h,
                                                half_t* __restrict__ k_h,
                                                half_t* __restrict__ vT) {
  const int bx = blockIdx.x, by = blockIdx.y;
  const int tid = threadIdx.x;
  const int w = tid >> 6, lane = tid & 63;
  const int lr = lane & 15, lk = (lane >> 4) * 8, lg = lane >> 4;

  const half_t* A;
  const half_t* W;
  int mode, rt0;
  if (bx < 32)      { A = x_h;   W = qk_h; mode = 0; rt0 = bx * 64; }
  else if (bx < 52) { A = anc_h; W = qk_h; mode = 1; rt0 = (bx - 32) * 64; }
  else              { A = x_h;   W = v_wh; mode = 2; rt0 = (bx - 52) * 64; }

  const int row0 = rt0 + w * 16;
  const int col0 = by * 64;
  const f4 fz = {0.f, 0.f, 0.f, 0.f};
  f4 acc[4] = {fz, fz, fz, fz};
  const half_t* arow = A + (size_t)(row0 + lr) * DIM;

  if (mode != 2) {
    for (int k0 = 0; k0 < DIM; k0 += 32) {
      h8 a = *(const h8*)(arow + k0 + lk);
#pragma unroll
      for (int ct = 0; ct < 4; ++ct) {
        h8 b = *(const h8*)(W + (size_t)(col0 + ct * 16 + lr) * DIM + k0 + lk);
        acc[ct] = mfma16(a, b, acc[ct]);
      }
    }
    half_t* out = (mode == 0) ? q_h : k_h;
#pragma unroll
    for (int ct = 0; ct < 4; ++ct) {
      int col = col0 + ct * 16 + lr;
#pragma unroll
      for (int r = 0; r < 4; ++r) {
        int row = row0 + lg * 4 + r;
        out[(size_t)row * DIM + col] = (half_t)acc[ct][r];
      }
    }
  } else {
    for (int k0 = 0; k0 < DIM; k0 += 32) {
      h8 a = *(const h8*)(arow + k0 + lk);
#pragma unroll
      for (int ct = 0; ct < 4; ++ct) {
        h8 b = *(const h8*)(W + (size_t)(col0 + ct * 16 + lr) * DIM + k0 + lk);
        acc[ct] = mfma16(b, a, acc[ct]);
      }
    }
    const int xrow = row0 + lr;
#pragma unroll
    for (int ct = 0; ct < 4; ++ct) {
#pragma unroll
      for (int r = 0; r < 4; ++r) {
        int col = col0 + ct * 16 + lg * 4 + r;  // = h*64 + d
        vT[(size_t)col * (BB * NN) + xrow] = (half_t)acc[ct][r];
      }
    }
  }
}

// ---------------------------------------------------------------------------
// K2 v9 (path A): quarter-task blocks for 2-blocks/CU co-residency.
// 1280 blocks (task x m'-quarter) x 512 thr (8 waves).
//  P0: stage kst [256][64] swz (region 0).
//  P1: two passes (16 rows each): a0 rows w*32+p*16 streamed v5-style
//      (Lb bounce -> La[2][8] regs); quarter-owning waves (w>>1 == qt) write
//      fp32 a0 to d_out + fp16 to a0s [64][256] swz.
//  S: per wave [32 n (own La rows)][64 m' (quarter)]: 4 R-reads + 8 MFMA /kc.
//  softmax: wave (max,sum) -> scr (overlaid in dead kst region), combine by
//      tid<64 -> scr2, fold fac*wgt into sacc.
//  PV: per 32-m' panel via per-wave [32][36] bounce (also in kst region);
//      v fragments straight from L2-hot vT. Partial U16[task*4+qt].
// LDS: kst 32K (scr 4K | scr2 .5K | pbuf 18K overlays) + a0s 32K + Lb 10K
//    = 75,776 B -> 2 blocks/CU. VGPR ~115 -> 4 waves/SIMD, 16 waves/CU.
// ---------------------------------------------------------------------------
__global__ __launch_bounds__(512, 4) void fused_attn9(const half_t* __restrict__ q_h,
                                                      const half_t* __restrict__ k_h,
                                                      const half_t* __restrict__ vT,
                                                      const float* __restrict__ weights,
                                                      float* __restrict__ a0_base,
                                                      half_t* __restrict__ U16) {
  extern __shared__ char smem[];
  half_t* kst = (half_t*)smem;                   // [256][64] swz, 32768 B
  half_t* a0s = (half_t*)(smem + 32768);         // [64][256] swz, 32768 B
  half_t* lbuf = (half_t*)(smem + 65536);        // 8 x [16][40] = 10240 B
  float2* scr = (float2*)smem;                   // overlay: [8][64] f2, 4096 B
  float2* scr2 = (float2*)(smem + 4096);         // overlay: [64] f2, 512 B
  half_t* pbuf = (half_t*)(smem + 4608);         // overlay: 8 x [32][36], 18432 B

  const int bid = blockIdx.x;  // 1280
  const int task = bid >> 2, qt = bid & 3;
  const int b = task / 40;
  const int rem = task % 40;
  const int c = rem / 8;
  const int h = rem & 7;

  const int tid = threadIdx.x;
  const int w = tid >> 6, lane = tid & 63;  // 8 waves
  const int lr = lane & 15, lk = (lane >> 4) * 8, lg = lane >> 4;

  const half_t* qb = q_h + (size_t)(b * NN) * DIM + h * HD;
  const half_t* kb = k_h + (size_t)(c * NN) * DIM + h * HD;
  const half_t* vTb = vT + (size_t)(h * HD) * (BB * NN) + b * NN;
  float* a0out = a0_base + (size_t)((b * NC + c) * NH + h) * (NN * NN);
  const float wgt = weights[(b * NH + h) * NC + c];
  const f4 fz = {0.f, 0.f, 0.f, 0.f};

  // ---- P0: stage k tile [256][64] ----
#pragma unroll
  for (int pass = 0; pass < 4; ++pass) {
    int slot = pass * 512 + tid;
    int row = slot >> 3, k8 = (slot & 7) * 8;
    *(h8*)(kst + ((row * 64 + k8) ^ ((row & 7) << 3))) =
        *(const h8*)(kb + (size_t)row * DIM + k8);
  }
  barrier_lds();  // A

  // ---- P1: two 16-row passes; build La[2][8]; owners write a0 ----
  half_t* Lb = lbuf + w * 640;  // [16][40]
  h8 La[2][8];
  const bool own = ((w >> 1) == qt);
#pragma unroll
  for (int p = 0; p < 2; ++p) {
    const int nbase = w * 32 + p * 16;
    h8 qf0 = *(const h8*)(qb + (size_t)(nbase + lr) * DIM + lk);
    h8 qf1 = *(const h8*)(qb + (size_t)(nbase + lr) * DIM + 32 + lk);
    const int row_l = (w & 1) * 32 + p * 16 + lr;  // a0s local row (if own)
#pragma unroll
    for (int mt = 0; mt < 16; ++mt) {
      const int krow = mt * 16 + lr;
      h8 kf0 = *(const h8*)(kst + ((krow * 64 + lk) ^ ((krow & 7) << 3)));
      h8 kf1 = *(const h8*)(kst + ((krow * 64 + 32 + lk) ^ ((krow & 7) << 3)));
      f4 acc = mfma16(kf0, qf0, fz);
      acc = mfma16(kf1, qf1, acc);
      f4 v0;
      h4 hv;
#pragma unroll
      for (int r = 0; r < 4; ++r) {
        v0[r] = acc[r] * 0.125f;
        hv[r] = (_Float16)v0[r];
      }
      *(h4*)(Lb + lr * 40 + (mt & 1) * 16 + lg * 4) = hv;
      if (own) {
        *(f4*)(a0out + (size_t)(nbase + lr) * NN + mt * 16 + lg * 4) = v0;
        *(h4*)(a0s + ((row_l * NN + mt * 16 + lg * 4) ^ ((row_l & 7) << 3))) = hv;
      }
      if (mt & 1) {
        h8 raw = *(const h8*)(Lb + lr * 40 + lg * 8);
        La[p][mt >> 1] = relu_neg_h8(raw);
      }
    }
  }
  barrier_lds();  // B: a0s complete; kst dead

  // ---- S = relu(-a0) @ relu(a0_quarter)^T: wave tile [32 n][64 m'] ----
  f4 sacc[4][2];
#pragma unroll
  for (int ct = 0; ct < 4; ++ct) {
    sacc[ct][0] = fz;
    sacc[ct][1] = fz;
  }
#pragma unroll
  for (int kc = 0; kc < 8; ++kc) {
#pragma unroll
    for (int ct = 0; ct < 4; ++ct) {
      const int rr = ct * 16 + lr;  // a0s local row (quarter m')
      h8 R = relu_pos_h8(*(const h8*)(a0s + ((rr * NN + kc * 32 + lk) ^ ((rr & 7) << 3))));
      sacc[ct][0] = mfma16(La[0][kc], R, sacc[ct][0]);
      sacc[ct][1] = mfma16(La[1][kc], R, sacc[ct][1]);
    }
  }

  // ---- softmax over n per m'-col: wave-local (max,sum), exp in place ----
  float mw[4];
#pragma unroll
  for (int ct = 0; ct < 4; ++ct) {
    float v = 0.f;  // S >= 0 always
#pragma unroll
    for (int rt = 0; rt < 2; ++rt)
#pragma unroll
      for (int r = 0; r < 4; ++r) v = fmaxf(v, sacc[ct][rt][r]);
    v = fmaxf(v, __shfl_xor(v, 16, 64));
    v = fmaxf(v, __shfl_xor(v, 32, 64));
    mw[ct] = v;
    float s = 0.f;
#pragma unroll
    for (int rt = 0; rt < 2; ++rt)
#pragma unroll
      for (int r = 0; r < 4; ++r) {
        float e = __expf(sacc[ct][rt][r] - v);
        sacc[ct][rt][r] = e;
        s += e;
      }
    s += __shfl_xor(s, 16, 64);
    s += __shfl_xor(s, 32, 64);
    if (lane < 16) {
      float2 t;
      t.x = v;
      t.y = s;
      scr[w * 64 + ct * 16 + lr] = t;  // kst region: dead after barrier B
    }
  }
  barrier_lds();  // C

  // ---- combine across 8 waves (tid<64, one m'-column each) ----
  if (tid < 64) {
    float gm = 0.f;
    float sg = 0.f;
    float2 t[8];
#pragma unroll
    for (int ww = 0; ww < 8; ++ww) {
      t[ww] = scr[ww * 64 + tid];
      gm = fmaxf(gm, t[ww].x);
    }
#pragma unroll
    for (int ww = 0; ww < 8; ++ww) sg += t[ww].y * __expf(t[ww].x - gm);
    float2 r;
    r.x = gm;
    r.y = sg;
    scr2[tid] = r;
  }
  barrier_lds();  // D

  // fold fac into P
#pragma unroll
  for (int ct = 0; ct < 4; ++ct) {
    float2 t = scr2[ct * 16 + lr];
    float fac = __expf(mw[ct] - t.x) * wgt / t.y;
#pragma unroll
    for (int rt = 0; rt < 2; ++rt)
#pragma unroll
      for (int r = 0; r < 4; ++r) sacc[ct][rt][r] *= fac;
  }

  // ---- PV per 32-m' panel: transpose-bounce P ([m'][n] layout) ----
  half_t* pbw = pbuf + w * 1152;  // [32][36]
  f4 uacc[4][2];
#pragma unroll
  for (int dt = 0; dt < 4; ++dt) {
    uacc[dt][0] = fz;
    uacc[dt][1] = fz;
  }
#pragma unroll
  for (int p2 = 0; p2 < 2; ++p2) {
#pragma unroll
    for (int ctl = 0; ctl < 2; ++ctl) {
      const int ct = p2 * 2 + ctl;
#pragma unroll
      for (int rt = 0; rt < 2; ++rt) {
        h4 hv;
#pragma unroll
        for (int r = 0; r < 4; ++r) hv[r] = (_Float16)sacc[ct][rt][r];
        *(h4*)(pbw + (ctl * 16 + lr) * 36 + rt * 16 + lg * 4) = hv;
      }
    }
    h8 pf0, pf1;
#pragma unroll
    for (int e = 0; e < 8; ++e) {
      pf0[e] = pbw[(lg * 8 + e) * 36 + lr];
      pf1[e] = pbw[(lg * 8 + e) * 36 + 16 + lr];
    }
#pragma unroll
    for (int dt = 0; dt < 4; ++dt) {
      h8 vf = *(const h8*)(vTb + (size_t)(dt * 16 + lr) * (BB * NN) + qt * 64 + p2 * 32 + lg * 8);
      uacc[dt][0] = mfma16(vf, pf0, uacc[dt][0]);
      uacc[dt][1] = mfma16(vf, pf1, uacc[dt][1]);
    }
  }

  // ---- store partial U16 (fp16) [n][d], slot = task*4 + qt ----
  half_t* Ub = U16 + (size_t)(task * 4 + qt) * (NN * HD);
#pragma unroll
  for (int dt = 0; dt < 4; ++dt)
#pragma unroll
    for (int nt = 0; nt < 2; ++nt) {
      int n = w * 32 + nt * 16 + lr;
      h4 hv;
#pragma unroll
      for (int r = 0; r < 4; ++r) hv[r] = (_Float16)uacc[dt][nt][r];
      *(h4*)(Ub + (size_t)n * HD + dt * 16 + lg * 4) = hv;
    }
}

// ---------------------------------------------------------------------------
// K3a (path A): out_head[b,h] = sum over (c, quarter) of U16 partials (20)
// ---------------------------------------------------------------------------
__global__ __launch_bounds__(256) void reduce_u20(const half_t* __restrict__ U16,
                                                  half_t* __restrict__ out_head) {
  int t = blockIdx.x * 256 + threadIdx.x;  // 131072 threads
  int bh = t >> 11;
  int e = (t & 2047) * 8;
  int b = bh >> 3, h = bh & 7;
  float acc[8] = {0.f, 0.f, 0.f, 0.f, 0.f, 0.f, 0.f, 0.f};
#pragma unroll
  for (int c = 0; c < NC; ++c)
#pragma unroll
    for (int qq = 0; qq < 4; ++qq) {
      h8 u = *(const h8*)(U16 + (size_t)(((b * NC + c) * NH + h) * 4 + qq) * (NN * HD) + e);
#pragma unroll
      for (int j = 0; j < 8; ++j) acc[j] += (float)u[j];
    }
  h8 o;
#pragma unroll
  for (int j = 0; j < 8; ++j) o[j] = (_Float16)acc[j];
  *(h8*)(out_head + (size_t)bh * (NN * HD) + e) = o;
}

// ---------------------------------------------------------------------------
// K2 (path B fallback, round-8 winner verbatim): 2 half-blocks/(b,c,h).
// ---------------------------------------------------------------------------
__global__ __launch_bounds__(1024, 4) void fused_attn5(const half_t* __restrict__ q_h,
                                                       const half_t* __restrict__ k_h,
                                                       const half_t* __restrict__ vT,
                                                       const float* __restrict__ weights,
                                                       float* __restrict__ a0_base,
                                                       half_t* __restrict__ U4) {
  extern __shared__ char smem[];
  half_t* a0s = (half_t*)smem;                        // [128][256] swz, 65536 B
  half_t* kst = (half_t*)(smem + 65536);              // [256][64] swz, 32768 B
  half_t* vst = kst;                                  // reuse: [64][128] swz
  half_t* wbuf = (half_t*)(smem + 98304);             // 16 waves x 640 h
  float2* scr = (float2*)(smem + 118784);             // [16 w][128 m'] f2
  float2* scr2 = (float2*)(smem + 135168);            // [128 m'] f2

  const int id = blockIdx.x;  // 640
  const int b = id / 80;
  const int rem = id % 80;
  const int c = rem / 16;
  const int h = (rem >> 1) & 7;
  const int q = rem & 1;

  const int tid = threadIdx.x;
  const int w = tid >> 6, lane = tid & 63;
  const int lr = lane & 15, lk = (lane >> 4) * 8, lg = lane >> 4;
  const int n0 = w * 16;

  const half_t* qb = q_h + (size_t)(b * NN) * DIM + h * HD;
  const half_t* kb = k_h + (size_t)(c * NN) * DIM + h * HD;
  const half_t* vTb = vT + (size_t)(h * HD) * (BB * NN) + b * NN;
  float* a0out = a0_base + (size_t)((b * NC + c) * NH + h) * (NN * NN);
  const float wgt = weights[(b * NH + h) * NC + c];

  const f4 fz = {0.f, 0.f, 0.f, 0.f};

  h8 qf0 = *(const h8*)(qb + (size_t)(n0 + lr) * DIM + lk);
  h8 qf1 = *(const h8*)(qb + (size_t)(n0 + lr) * DIM + 32 + lk);

#pragma unroll
  for (int pass = 0; pass < 2; ++pass) {
    int slot = pass * 1024 + tid;
    int row = slot >> 3, k8 = (slot & 7) * 8;
    h8 val = *(const h8*)(kb + (size_t)row * DIM + k8);
    *(h8*)(kst + ((row * 64 + k8) ^ ((row & 7) << 3))) = val;
  }
  barrier_lds();

  half_t* Lb = wbuf + w * 640;
  h8 La[8];
  const bool myhalf = ((w >> 3) == q);
  const int rl = (w & 7) * 16 + lr;
#pragma unroll
  for (int mt = 0; mt < 16; ++mt) {
    const int krow = mt * 16 + lr;
    h8 kf0 = *(const h8*)(kst + ((krow * 64 + lk) ^ ((krow & 7) << 3)));
    h8 kf1 = *(const h8*)(kst + ((krow * 64 + 32 + lk) ^ ((krow & 7) << 3)));
    f4 acc = mfma16(kf0, qf0, fz);
    acc = mfma16(kf1, qf1, acc);
    f4 v0;
    h4 hv;
#pragma unroll
    for (int r = 0; r < 4; ++r) {
      v0[r] = acc[r] * 0.125f;
      hv[r] = (_Float16)v0[r];
    }
    *(h4*)(Lb + lr * 40 + (mt & 1) * 16 + lg * 4) = hv;
    if (myhalf) {
      *(f4*)(a0out + (size_t)(n0 + lr) * NN + mt * 16 + lg * 4) = v0;
      *(h4*)(a0s + ((rl * 256 + mt * 16 + lg * 4) ^ ((rl & 7) << 3))) = hv;
    }
    if (mt & 1) {
      h8 raw = *(const h8*)(Lb + lr * 40 + lg * 8);
      La[mt >> 1] = relu_neg_h8(raw);
    }
  }
  barrier_lds();

  {
    int d = tid >> 4, m8 = (tid & 15) * 8;
    h8 val = *(const h8*)(vTb + (size_t)d * (BB * NN) + q * 128 + m8);
    *(h8*)(vst + ((d * 128 + m8) ^ ((d & 7) << 4))) = val;
  }

  f4 sacc[8];
#pragma unroll
  for (int ct = 0; ct < 8; ++ct) sacc[ct] = fz;
#pragma unroll
  for (int kc = 0; kc < 8; ++kc) {
#pragma unroll
    for (int ct = 0; ct < 8; ++ct) {
      const int rr = ct * 16 + lr;
      h8 R = relu_pos_h8(*(const h8*)(a0s + ((rr * 256 + kc * 32 + lk) ^ ((rr & 7) << 3))));
      sacc[ct] = mfma16(La[kc], R, sacc[ct]);
    }
  }

  float mw[8];
#pragma unroll
  for (int ct = 0; ct < 8; ++ct) {
    float v = 0.f;
#pragma unroll
    for (int r = 0; r < 4; ++r) v = fmaxf(v, sacc[ct][r]);
    v = fmaxf(v, __shfl_xor(v, 16, 64));
    v = fmaxf(v, __shfl_xor(v, 32, 64));
    mw[ct] = v;
    float s = 0.f;
#pragma unroll
    for (int r = 0; r < 4; ++r) {
      float e = __expf(sacc[ct][r] - v);
      sacc[ct][r] = e;
      s += e;
    }
    s += __shfl_xor(s, 16, 64);
    s += __shfl_xor(s, 32, 64);
    if (lane < 16) {
      float2 t;
      t.x = v;
      t.y = s;
      scr[w * 128 + ct * 16 + lr] = t;
    }
  }
  barrier_lds();

  if (tid < 128) {
    float gm = 0.f;
#pragma unroll
    for (int ww = 0; ww < 16; ++ww) gm = fmaxf(gm, scr[ww * 128 + tid].x);
    float sg = 0.f;
#pragma unroll
    for (int ww = 0; ww < 16; ++ww) {
      float2 t = scr[ww * 128 + tid];
      sg += t.y * __expf(t.x - gm);
    }
    float2 r;
    r.x = gm;
    r.y = sg;
    scr2[tid] = r;
  }
  barrier_lds();

  float fac[8];
#pragma unroll
  for (int ct = 0; ct < 8; ++ct) {
    float2 t = scr2[ct * 16 + lr];
    fac[ct] = __expf(mw[ct] - t.x) * wgt / t.y;
  }

  half_t* pbw = wbuf + w * 640;
  f4 uacc[4] = {fz, fz, fz, fz};
#pragma unroll
  for (int pan = 0; pan < 4; ++pan) {
#pragma unroll
    for (int ctl = 0; ctl < 2; ++ctl) {
      const int ct = pan * 2 + ctl;
      h4 hv;
#pragma unroll
      for (int r = 0; r < 4; ++r) hv[r] = (_Float16)(sacc[ct][r] * fac[ct]);
      *(h4*)(pbw + (ctl * 16 + lr) * 20 + lg * 4) = hv;
    }
    h8 pf;
#pragma unroll
    for (int e = 0; e < 8; ++e) pf[e] = pbw[(lg * 8 + e) * 20 + lr];
#pragma unroll
    for (int dt = 0; dt < 4; ++dt) {
      const int dr = dt * 16 + lr;
      h8 vf = *(const h8*)(vst + ((dr * 128 + pan * 32 + lk) ^ ((dr & 7) << 4)));
      uacc[dt] = mfma16(vf, pf, uacc[dt]);
    }
  }

  half_t* U4b = U4 + (size_t)(((b * NC + c) * NH + h) * 2 + q) * (NN * HD);
#pragma unroll
  for (int dt = 0; dt < 4; ++dt) {
    h4 hv;
#pragma unroll
    for (int r = 0; r < 4; ++r) hv[r] = (_Float16)uacc[dt][r];
    *(h4*)(U4b + (size_t)(n0 + lr) * HD + dt * 16 + lg * 4) = hv;
  }
}

// ---------------------------------------------------------------------------
// K3b (path B): out_head = sum over (c, half) of U4 partials (10)
// ---------------------------------------------------------------------------
__global__ __launch_bounds__(256) void reduce_u(const half_t* __restrict__ U4,
                                                half_t* __restrict__ out_head) {
  int t = blockIdx.x * 256 + threadIdx.x;
  int bh = t >> 11;
  int e = (t & 2047) * 8;
  int b = bh >> 3, h = bh & 7;
  float acc[8] = {0.f, 0.f, 0.f, 0.f, 0.f, 0.f, 0.f, 0.f};
#pragma unroll
  for (int c = 0; c < NC; ++c)
#pragma unroll
    for (int qq = 0; qq < 2; ++qq) {
      h8 u = *(const h8*)(U4 + (size_t)(((b * NC + c) * NH + h) * 2 + qq) * (NN * HD) + e);
#pragma unroll
      for (int j = 0; j < 8; ++j) acc[j] += (float)u[j];
    }
  h8 o;
#pragma unroll
  for (int j = 0; j < 8; ++j) o[j] = (_Float16)acc[j];
  *(h8*)(out_head + (size_t)bh * (NN * HD) + e) = o;
}

// ---------------------------------------------------------------------------
// K4: out0 = reshape(out_head) @ pw_h^T + proj_b  (fp16 weights)
// ---------------------------------------------------------------------------
__global__ __launch_bounds__(256) void out_proj(const half_t* __restrict__ out_head,
                                                const half_t* __restrict__ pw_h,
                                                const float* __restrict__ pb,
                                                float* __restrict__ out0) {
  const int tid = threadIdx.x;
  const int w = tid >> 6, lane = tid & 63;
  const int lr = lane & 15, lk = (lane >> 4) * 8, lg = lane >> 4;
  const int row0 = blockIdx.x * 64 + w * 16;
  const int col0 = blockIdx.y * 64;
  const int r_ = row0 + lr;
  const int b = r_ >> 8, i = r_ & 255;
  const int hh = i >> 5;
  const f4 fz = {0.f, 0.f, 0.f, 0.f};
  f4 acc[4] = {fz, fz, fz, fz};
  for (int k0 = 0; k0 < DIM; k0 += 32) {
    const int k = k0 + lk;
    const int n = ((i & 31) << 3) | (k >> 6);
    const int d = k & 63;
    h8 a = *(const h8*)(out_head + (size_t)((b * NH + hh) * NN + n) * HD + d);
#pragma unroll
    for (int ct = 0; ct < 4; ++ct) {
      h8 bf = *(const h8*)(pw_h + (size_t)(col0 + ct * 16 + lr) * DIM + k0 + lk);
      acc[ct] = mfma16(a, bf, acc[ct]);
    }
  }
#pragma unroll
  for (int ct = 0; ct < 4; ++ct) {
    int col = col0 + ct * 16 + lr;
    float bias = pb[col];
#pragma unroll
    for (int r = 0; r < 4; ++r) {
      int row = row0 + lg * 4 + r;
      out0[(size_t)row * DIM + col] = acc[ct][r] + bias;
    }
  }
}

// ---------------------------------------------------------------------------
extern "C" void kernel_launch(void* const* d_in, const int* in_sizes, int n_in,
                              void* d_out, int out_size, void* d_ws, size_t ws_size,
                              hipStream_t stream) {
  const float* x = (const float*)d_in[0];
  const float* anchors = (const float*)d_in[1];
  const float* weights = (const float*)d_in[2];
  const float* qk_w = (const float*)d_in[3];
  const float* v_w = (const float*)d_in[4];
  const float* proj_w = (const float*)d_in[5];
  const float* proj_b = (const float*)d_in[6];

  float* out0 = (float*)d_out;                       // [8,256,512]
  float* a0_out = out0 + (size_t)BB * NN * DIM;      // [8,5,8,256,256]

  char* ws = (char*)d_ws;
  const size_t MB = 1024 * 1024;

  // Path A layout (needs ~47.8 MB): U16 40MB @0 (staging overlaid), then
  // pw_h/q_h/k_h/vT/out_head.
  const size_t A_U16 = 0;
  const size_t A_pw = (size_t)1280 * NN * HD * 2;          // 41,943,040
  const size_t A_q = A_pw + 524288;
  const size_t A_k = A_q + 2097152;
  const size_t A_vT = A_k + 1310720;
  const size_t A_oh = A_vT + 2097152;
  const size_t A_need = A_oh + 2097152;  // 50,069,504

  if (ws_size >= A_need) {
    half_t* x_h   = (half_t*)(ws);            // staging (overlaid by U16 later)
    half_t* anc_h = (half_t*)(ws + 2 * MB);
    half_t* qk_h  = (half_t*)(ws + 3407872);
    half_t* v_wh  = (half_t*)(ws + 3932160);
    half_t* U16   = (half_t*)(ws + A_U16);
    half_t* pw_h  = (half_t*)(ws + A_pw);
    half_t* q_h   = (half_t*)(ws + A_q);
    half_t* k_h   = (half_t*)(ws + A_k);
    half_t* vT    = (half_t*)(ws + A_vT);
    half_t* out_head = (half_t*)(ws + A_oh);

    cvt_all<<<dim3(2432), 256, 0, stream>>>(x, anchors, qk_w, v_w, proj_w,
                                            x_h, anc_h, qk_h, v_wh, pw_h);
    proj_all<<<dim3(84, 8), 256, 0, stream>>>(x_h, anc_h, qk_h, v_wh, q_h, k_h, vT);

    const size_t lds9 = 32768 + 32768 + 10240;  // 75,776 B -> 2 blocks/CU
    fused_attn9<<<dim3(BB * NC * NH * 4), 512, lds9, stream>>>(q_h, k_h, vT, weights,
                                                               a0_out, U16);
    reduce_u20<<<dim3(512), 256, 0, stream>>>(U16, out_head);
    out_proj<<<dim3(32, 8), 256, 0, stream>>>(out_head, pw_h, proj_b, out0);
  } else {
    // Path B: round-8 configuration (28 MB)
    half_t* x_h   = (half_t*)(ws);
    half_t* anc_h = (half_t*)(ws + 2 * MB);
    half_t* qk_h  = (half_t*)(ws + 3407872);
    half_t* v_wh  = (half_t*)(ws + 3932160);
    half_t* U4    = (half_t*)(ws);  // 20 MB overlay
    half_t* pw_h     = (half_t*)(ws + 20 * MB);
    half_t* q_h      = (half_t*)(ws + 20 * MB + 524288);
    half_t* k_h      = (half_t*)(ws + 22 * MB + 524288);
    half_t* vT       = (half_t*)(ws + 24 * MB);
    half_t* out_head = (half_t*)(ws + 26 * MB);

    cvt_all<<<dim3(2432), 256, 0, stream>>>(x, anchors, qk_w, v_w, proj_w,
                                            x_h, anc_h, qk_h, v_wh, pw_h);
    proj_all<<<dim3(84, 8), 256, 0, stream>>>(x_h, anc_h, qk_h, v_wh, q_h, k_h, vT);

    const size_t lds5 = 65536 + 32768 + 20480 + 16384 + 1024;
    fused_attn5<<<dim3(BB * NC * NH * 2), 1024, lds5, stream>>>(q_h, k_h, vT, weights,
                                                                a0_out, U4);
    reduce_u<<<dim3(512), 256, 0, stream>>>(U4, out_head);
    out_proj<<<dim3(32, 8), 256, 0, stream>>>(out_head, pw_h, proj_b, out0);
  }

  (void)in_sizes; (void)n_in; (void)out_size;
}

// Round 12
// 149.605 us; speedup vs baseline: 1.1031x; 1.0085x over previous
//
#include <hip/hip_runtime.h>
#include <hip/hip_fp16.h>
#include <cstdint>

// Problem constants
#define BB 8
#define NN 256
#define NC 5
#define NH 8
#define DIM 512
#define HD 64

typedef _Float16 half_t;
typedef _Float16 h8 __attribute__((ext_vector_type(8)));
typedef _Float16 h4 __attribute__((ext_vector_type(4)));
typedef float f4 __attribute__((ext_vector_type(4)));
typedef uint32_t u4v __attribute__((ext_vector_type(4)));

__device__ __forceinline__ f4 mfma16(h8 a, h8 b, f4 c) {
  return __builtin_amdgcn_mfma_f32_16x16x32_f16(a, b, c, 0, 0, 0);
}

static __device__ const h8 HZERO = {(_Float16)0, (_Float16)0, (_Float16)0, (_Float16)0,
                                    (_Float16)0, (_Float16)0, (_Float16)0, (_Float16)0};

__device__ __forceinline__ h8 relu_pos_h8(h8 x) {
#if __has_builtin(__builtin_elementwise_max)
  return __builtin_elementwise_max(x, HZERO);
#else
  u4v u = __builtin_bit_cast(u4v, x);
  const u4v k1 = {0x00010001u, 0x00010001u, 0x00010001u, 0x00010001u};
  u4v s = (u >> 15) & k1;
  u4v m = (s << 16) - s;
  u = u & ~m;
  return __builtin_bit_cast(h8, u);
#endif
}

__device__ __forceinline__ h8 relu_neg_h8(h8 x) {
#if __has_builtin(__builtin_elementwise_max)
  return __builtin_elementwise_max(-x, HZERO);
#else
  u4v u = __builtin_bit_cast(u4v, x);
  const u4v k1 = {0x00010001u, 0x00010001u, 0x00010001u, 0x00010001u};
  const u4v ks = {0x80008000u, 0x80008000u, 0x80008000u, 0x80008000u};
  u4v s = (u >> 15) & k1;
  u4v m = (s << 16) - s;
  u = (u ^ ks) & m;
  return __builtin_bit_cast(h8, u);
#endif
}

// Raw barrier: waits LDS only, does NOT drain vmcnt (global stores stay in flight).
__device__ __forceinline__ void barrier_lds() {
  __builtin_amdgcn_sched_barrier(0);
  asm volatile("s_waitcnt lgkmcnt(0)" ::: "memory");
  __builtin_amdgcn_s_barrier();
  asm volatile("" ::: "memory");
  __builtin_amdgcn_sched_barrier(0);
}

// a0-block buffer access: [256 tokens][32 m] fp16, h8-slot XOR swizzle.
__device__ __forceinline__ h8 ab_read(const half_t* buf, int row, int lg) {
  int slot = lg ^ ((row ^ (row >> 2)) & 3);
  return *(const h8*)(buf + row * 32 + slot * 8);
}

// ---------------------------------------------------------------------------
// K0: convert x, anchors, qk_w, v_w, proj_w to fp16.
// ---------------------------------------------------------------------------
__global__ __launch_bounds__(256) void cvt_all(const float* __restrict__ x,
                                               const float* __restrict__ anchors,
                                               const float* __restrict__ qk_w,
                                               const float* __restrict__ v_w,
                                               const float* __restrict__ proj_w,
                                               half_t* __restrict__ x_h,
                                               half_t* __restrict__ anc_h,
                                               half_t* __restrict__ qk_h,
                                               half_t* __restrict__ v_wh,
                                               half_t* __restrict__ pw_h) {
  int i = blockIdx.x * 256 + threadIdx.x;
  const float* src;
  half_t* dst;
  int off;
  if (i < 262144)      { src = x;       dst = x_h;   off = i; }
  else if (i < 425984) { src = anchors; dst = anc_h; off = i - 262144; }
  else if (i < 491520) { src = qk_w;    dst = qk_h;  off = i - 425984; }
  else if (i < 557056) { src = v_w;     dst = v_wh;  off = i - 491520; }
  else                 { src = proj_w;  dst = pw_h;  off = i - 557056; }
  float4 v = ((const float4*)src)[off];
  h4 o;
  o[0] = (_Float16)v.x; o[1] = (_Float16)v.y; o[2] = (_Float16)v.z; o[3] = (_Float16)v.w;
  ((h4*)dst)[off] = o;
}

// ---------------------------------------------------------------------------
// K1: all three projections (pure fp16 operands).
// ---------------------------------------------------------------------------
__global__ __launch_bounds__(256) void proj_all(const half_t* __restrict__ x_h,
                                                const half_t* __restrict__ anc_h,
                                                const half_t* __restrict__ qk_h,
                                                const half_t* __restrict__ v_wh,
                                                half_t* __restrict__ q_h,
                                                half_t* __restrict__ k_h,
                                                half_t* __restrict__ vT) {
  const int bx = blockIdx.x, by = blockIdx.y;
  const int tid = threadIdx.x;
  const int w = tid >> 6, lane = tid & 63;
  const int lr = lane & 15, lk = (lane >> 4) * 8, lg = lane >> 4;

  const half_t* A;
  const half_t* W;
  int mode, rt0;
  if (bx < 32)      { A = x_h;   W = qk_h; mode = 0; rt0 = bx * 64; }
  else if (bx < 52) { A = anc_h; W = qk_h; mode = 1; rt0 = (bx - 32) * 64; }
  else              { A = x_h;   W = v_wh; mode = 2; rt0 = (bx - 52) * 64; }

  const int row0 = rt0 + w * 16;
  const int col0 = by * 64;
  const f4 fz = {0.f, 0.f, 0.f, 0.f};
  f4 acc[4] = {fz, fz, fz, fz};
  const half_t* arow = A + (size_t)(row0 + lr) * DIM;

  if (mode != 2) {
    for (int k0 = 0; k0 < DIM; k0 += 32) {
      h8 a = *(const h8*)(arow + k0 + lk);
#pragma unroll
      for (int ct = 0; ct < 4; ++ct) {
        h8 b = *(const h8*)(W + (size_t)(col0 + ct * 16 + lr) * DIM + k0 + lk);
        acc[ct] = mfma16(a, b, acc[ct]);
      }
    }
    half_t* out = (mode == 0) ? q_h : k_h;
#pragma unroll
    for (int ct = 0; ct < 4; ++ct) {
      int col = col0 + ct * 16 + lr;
#pragma unroll
      for (int r = 0; r < 4; ++r) {
        int row = row0 + lg * 4 + r;
        out[(size_t)row * DIM + col] = (half_t)acc[ct][r];
      }
    }
  } else {
    for (int k0 = 0; k0 < DIM; k0 += 32) {
      h8 a = *(const h8*)(arow + k0 + lk);
#pragma unroll
      for (int ct = 0; ct < 4; ++ct) {
        h8 b = *(const h8*)(W + (size_t)(col0 + ct * 16 + lr) * DIM + k0 + lk);
        acc[ct] = mfma16(b, a, acc[ct]);
      }
    }
    const int xrow = row0 + lr;
#pragma unroll
    for (int ct = 0; ct < 4; ++ct) {
#pragma unroll
      for (int r = 0; r < 4; ++r) {
        int col = col0 + ct * 16 + lg * 4 + r;  // = h*64 + d
        vT[(size_t)col * (BB * NN) + xrow] = (half_t)acc[ct][r];
      }
    }
  }
}

// ---------------------------------------------------------------------------
// K2 v10: k-blocked S accumulation. 640 blocks (task x m'-half) x 512 thr
// (8 waves). Wave w owns token rows [w*32, w*32+32).
//  mb loop (8 anchor-blocks of 32):
//    P(mb): a0[:, mb-block] = 0.125*(K[mb] @ q^T) -> fp16 dbuf LDS (XOR swz)
//           + fp32 a0 to d_out (mh==0 blocks only). K frags from L2, q in regs.
//    S(mb): sacc[8][2] += relu(-blk[n rows]) @ relu(blk[m' rows])^T
//           (both operands are rows of the SAME 16 KB block!)
//    software-pipelined: P(mb+1) issued before S(mb); 1 raw barrier per mb.
//  softmax over n per m'-col (2 LDS passes), fold fac*wgt into sacc.
//  PV per 32-m' panel ([32][42] bounce); v frags from L2-hot vT. U4 partials.
// LDS: dbuf 2x16K + scr 8K + scr2 1K = 41,984 B -> 2 blocks/CU (VGPR-capped).
// ---------------------------------------------------------------------------
__global__ __launch_bounds__(512, 4) void fused_attn10(const half_t* __restrict__ q_h,
                                                       const half_t* __restrict__ k_h,
                                                       const half_t* __restrict__ vT,
                                                       const float* __restrict__ weights,
                                                       float* __restrict__ a0_base,
                                                       half_t* __restrict__ U4) {
  extern __shared__ char smem[];
  half_t* ab0 = (half_t*)smem;                   // [256][32] swz, 16384 B
  half_t* ab1 = (half_t*)(smem + 16384);         // [256][32] swz, 16384 B
  float2* scr = (float2*)(smem + 32768);         // [8 w][128 m'], 8192 B
  float2* scr2 = (float2*)(smem + 40960);        // [128 m'] (gm,sg), 1024 B
  half_t* pbuf = (half_t*)smem;                  // overlay after S: 8 x [32][42]

  const int id = blockIdx.x;  // 640
  const int task = id >> 1, mh = id & 1;
  const int b = task / 40;
  const int rem = task % 40;
  const int c = rem / 8;
  const int h = rem & 7;

  const int tid = threadIdx.x;
  const int w = tid >> 6, lane = tid & 63;
  const int lr = lane & 15, lk = (lane >> 4) * 8, lg = lane >> 4;
  const int n0 = w * 32;

  const half_t* qb = q_h + (size_t)(b * NN) * DIM + h * HD;
  const half_t* kb = k_h + (size_t)(c * NN) * DIM + h * HD;
  const half_t* vTb = vT + (size_t)(h * HD) * (BB * NN) + b * NN;
  float* a0out = a0_base + (size_t)((b * NC + c) * NH + h) * (NN * NN);
  const float wgt = weights[(b * NH + h) * NC + c];
  const f4 fz = {0.f, 0.f, 0.f, 0.f};

  // q fragments for this wave's 32 rows (persistent, 16 VGPR)
  h8 qf[2][2];
#pragma unroll
  for (int nt = 0; nt < 2; ++nt)
#pragma unroll
    for (int kk = 0; kk < 2; ++kk)
      qf[nt][kk] = *(const h8*)(qb + (size_t)(n0 + nt * 16 + lr) * DIM + kk * 32 + lk);

  // a0-block producer: block mb -> buf (+ fp32 global store if mh==0)
#define P_BLOCK(mb, buf)                                                          \
  {                                                                               \
    _Pragma("unroll") for (int m_t = 0; m_t < 2; ++m_t) {                         \
      h8 kf0 = *(const h8*)(kb + (size_t)((mb)*32 + m_t * 16 + lr) * DIM + lk);   \
      h8 kf1 = *(const h8*)(kb + (size_t)((mb)*32 + m_t * 16 + lr) * DIM + 32 + lk); \
      _Pragma("unroll") for (int nt = 0; nt < 2; ++nt) {                          \
        f4 acc = mfma16(kf0, qf[nt][0], fz);                                      \
        acc = mfma16(kf1, qf[nt][1], acc);                                        \
        _Pragma("unroll") for (int r = 0; r < 4; ++r) acc[r] *= 0.125f;           \
        const int n = n0 + nt * 16 + lr;                                          \
        h4 hv;                                                                    \
        _Pragma("unroll") for (int r = 0; r < 4; ++r) hv[r] = (_Float16)acc[r];   \
        int slot = (m_t * 2 + (lg >> 1)) ^ ((n ^ (n >> 2)) & 3);                  \
        *(h4*)((buf) + n * 32 + slot * 8 + (lg & 1) * 4) = hv;                    \
        if (mh == 0)                                                              \
          *(f4*)(a0out + (size_t)n * NN + (mb)*32 + m_t * 16 + lg * 4) = acc;     \
      }                                                                           \
    }                                                                             \
  }

  f4 sacc[8][2];
#pragma unroll
  for (int ct = 0; ct < 8; ++ct) {
    sacc[ct][0] = fz;
    sacc[ct][1] = fz;
  }

  P_BLOCK(0, ab0);
  barrier_lds();

#pragma unroll
  for (int mb = 0; mb < 8; ++mb) {
    half_t* cur = (mb & 1) ? ab1 : ab0;
    half_t* nxt = (mb & 1) ? ab0 : ab1;
    if (mb < 7) P_BLOCK(mb + 1, nxt);
    // S accumulate from cur
    h8 La0 = relu_neg_h8(ab_read(cur, n0 + lr, lg));
    h8 La1 = relu_neg_h8(ab_read(cur, n0 + 16 + lr, lg));
#pragma unroll
    for (int ct = 0; ct < 8; ++ct) {
      const int rr = mh * 128 + ct * 16 + lr;
      h8 R = relu_pos_h8(ab_read(cur, rr, lg));
      sacc[ct][0] = mfma16(La0, R, sacc[ct][0]);
      sacc[ct][1] = mfma16(La1, R, sacc[ct][1]);
    }
    barrier_lds();
  }
#undef P_BLOCK

  // ---- softmax over n per m'-col: wave-local (max,sum), exp in place ----
  float mw[8];
#pragma unroll
  for (int ct = 0; ct < 8; ++ct) {
    float v = 0.f;  // S >= 0 always
#pragma unroll
    for (int nt = 0; nt < 2; ++nt)
#pragma unroll
      for (int r = 0; r < 4; ++r) v = fmaxf(v, sacc[ct][nt][r]);
    v = fmaxf(v, __shfl_xor(v, 16, 64));
    v = fmaxf(v, __shfl_xor(v, 32, 64));
    mw[ct] = v;
    float s = 0.f;
#pragma unroll
    for (int nt = 0; nt < 2; ++nt)
#pragma unroll
      for (int r = 0; r < 4; ++r) {
        float e = __expf(sacc[ct][nt][r] - v);
        sacc[ct][nt][r] = e;
        s += e;
      }
    s += __shfl_xor(s, 16, 64);
    s += __shfl_xor(s, 32, 64);
    if (lane < 16) {
      float2 t;
      t.x = v;
      t.y = s;
      scr[w * 128 + ct * 16 + lr] = t;
    }
  }
  barrier_lds();  // scr ready; all dbuf reads done

  // ---- combine across 8 waves (tid<128, one m'-column each) ----
  if (tid < 128) {
    float gm = 0.f;
    float sg = 0.f;
    float2 t[8];
#pragma unroll
    for (int ww = 0; ww < 8; ++ww) {
      t[ww] = scr[ww * 128 + tid];
      gm = fmaxf(gm, t[ww].x);
    }
#pragma unroll
    for (int ww = 0; ww < 8; ++ww) sg += t[ww].y * __expf(t[ww].x - gm);
    float2 r;
    r.x = gm;
    r.y = sg;
    scr2[tid] = r;
  }
  barrier_lds();  // scr2 ready; ab region fully dead -> pbuf usable

  // fold fac into P
#pragma unroll
  for (int ct = 0; ct < 8; ++ct) {
    float2 t = scr2[ct * 16 + lr];
    float fac = __expf(mw[ct] - t.x) * wgt / t.y;
#pragma unroll
    for (int nt = 0; nt < 2; ++nt)
#pragma unroll
      for (int r = 0; r < 4; ++r) sacc[ct][nt][r] *= fac;
  }

  // ---- PV per 32-m' panel: transpose-bounce P, v fragments from global ----
  half_t* pbw = pbuf + w * 1344;  // [32 m'][42 n-pad]
  f4 uacc[4][2];
#pragma unroll
  for (int dt = 0; dt < 4; ++dt) {
    uacc[dt][0] = fz;
    uacc[dt][1] = fz;
  }
#pragma unroll
  for (int p = 0; p < 4; ++p) {
#pragma unroll
    for (int ctl = 0; ctl < 2; ++ctl) {
      const int ct = p * 2 + ctl;
#pragma unroll
      for (int nt = 0; nt < 2; ++nt) {
        h4 hv;
#pragma unroll
        for (int r = 0; r < 4; ++r) hv[r] = (_Float16)sacc[ct][nt][r];
        *(h4*)(pbw + (ctl * 16 + lr) * 42 + nt * 16 + lg * 4) = hv;
      }
    }
    h8 pf0, pf1;
#pragma unroll
    for (int e = 0; e < 8; ++e) {
      pf0[e] = pbw[(lg * 8 + e) * 42 + lr];
      pf1[e] = pbw[(lg * 8 + e) * 42 + 16 + lr];
    }
#pragma unroll
    for (int dt = 0; dt < 4; ++dt) {
      h8 vf = *(const h8*)(vTb + (size_t)(dt * 16 + lr) * (BB * NN) + mh * 128 + p * 32 + lg * 8);
      uacc[dt][0] = mfma16(vf, pf0, uacc[dt][0]);
      uacc[dt][1] = mfma16(vf, pf1, uacc[dt][1]);
    }
  }

  // ---- store partial U4 (fp16): [n][d], slot = task*2 + mh ----
  half_t* U4b = U4 + (size_t)(task * 2 + mh) * (NN * HD);
#pragma unroll
  for (int dt = 0; dt < 4; ++dt)
#pragma unroll
    for (int nt = 0; nt < 2; ++nt) {
      int n = n0 + nt * 16 + lr;
      h4 hv;
#pragma unroll
      for (int r = 0; r < 4; ++r) hv[r] = (_Float16)uacc[dt][nt][r];
      *(h4*)(U4b + (size_t)n * HD + dt * 16 + lg * 4) = hv;
    }
}

// ---------------------------------------------------------------------------
// K3: merged reduce + out-projection. 64 blocks, one per (b, hh) = 32 rows.
// Stage reduced A-tile (sum of 10 U4 partials) in LDS, then GEMM + bias.
// ---------------------------------------------------------------------------
__global__ __launch_bounds__(256) void out_projA(const half_t* __restrict__ U4,
                                                 const half_t* __restrict__ pw_h,
                                                 const float* __restrict__ pb,
                                                 float* __restrict__ out0) {
  __shared__ half_t Ast[32 * 520];  // [32 rows][512 k + 8 pad]
  const int bid = blockIdx.x;       // 64
  const int b = bid >> 3, hh = bid & 7;
  const int tid = threadIdx.x;

  // stage: thread (il = tid>>3, kk = tid&7) reduces 10 partial slices
  {
    const int il = tid >> 3, kk = tid & 7;
    const int n = (il << 3) | kk;
    const half_t* base = U4 + ((size_t)(b * NC * NH + hh) * 2) * (NN * HD) + (size_t)n * HD;
#pragma unroll
    for (int d0 = 0; d0 < HD; d0 += 8) {
      float a8[8] = {0.f, 0.f, 0.f, 0.f, 0.f, 0.f, 0.f, 0.f};
#pragma unroll
      for (int cc = 0; cc < NC; ++cc)
#pragma unroll
        for (int qq = 0; qq < 2; ++qq) {
          h8 u = *(const h8*)(base + (size_t)(cc * NH * 2 + qq) * (NN * HD) + d0);
#pragma unroll
          for (int j = 0; j < 8; ++j) a8[j] += (float)u[j];
        }
      h8 o;
#pragma unroll
      for (int j = 0; j < 8; ++j) o[j] = (_Float16)a8[j];
      *(h8*)(&Ast[il * 520 + kk * 64 + d0]) = o;
    }
  }
  __syncthreads();

  // GEMM: 4 waves x 128 cols each, 32 rows
  const int w = tid >> 6, lane = tid & 63;
  const int lr = lane & 15, lk = (lane >> 4) * 8, lg = lane >> 4;
  const int col0 = w * 128;
  const f4 fz = {0.f, 0.f, 0.f, 0.f};
  f4 acc[2][8];
#pragma unroll
  for (int rt = 0; rt < 2; ++rt)
#pragma unroll
    for (int ct = 0; ct < 8; ++ct) acc[rt][ct] = fz;

  for (int kc = 0; kc < 16; ++kc) {
    h8 a0f = *(const h8*)(&Ast[(lr)*520 + kc * 32 + lk]);
    h8 a1f = *(const h8*)(&Ast[(16 + lr) * 520 + kc * 32 + lk]);
#pragma unroll
    for (int ct = 0; ct < 8; ++ct) {
      h8 bf = *(const h8*)(pw_h + (size_t)(col0 + ct * 16 + lr) * DIM + kc * 32 + lk);
      acc[0][ct] = mfma16(a0f, bf, acc[0][ct]);
      acc[1][ct] = mfma16(a1f, bf, acc[1][ct]);
    }
  }

  const int row_base = b * NN + hh * 32;
#pragma unroll
  for (int ct = 0; ct < 8; ++ct) {
    int col = col0 + ct * 16 + lr;
    float bias = pb[col];
#pragma unroll
    for (int rt = 0; rt < 2; ++rt)
#pragma unroll
      for (int r = 0; r < 4; ++r) {
        int row = row_base + rt * 16 + lg * 4 + r;
        out0[(size_t)row * DIM + col] = acc[rt][ct][r] + bias;
      }
  }
}

// ---------------------------------------------------------------------------
extern "C" void kernel_launch(void* const* d_in, const int* in_sizes, int n_in,
                              void* d_out, int out_size, void* d_ws, size_t ws_size,
                              hipStream_t stream) {
  const float* x = (const float*)d_in[0];
  const float* anchors = (const float*)d_in[1];
  const float* weights = (const float*)d_in[2];
  const float* qk_w = (const float*)d_in[3];
  const float* v_w = (const float*)d_in[4];
  const float* proj_w = (const float*)d_in[5];
  const float* proj_b = (const float*)d_in[6];

  float* out0 = (float*)d_out;                       // [8,256,512]
  float* a0_out = out0 + (size_t)BB * NN * DIM;      // [8,5,8,256,256]

  char* ws = (char*)d_ws;
  const size_t MB = 1024 * 1024;
  // Region 0..20MB: fp16 staging (dead before fused_attn10) then U4 overlay.
  half_t* x_h   = (half_t*)(ws);                  // 2 MB
  half_t* anc_h = (half_t*)(ws + 2 * MB);         // 1.25 MB
  half_t* qk_h  = (half_t*)(ws + 3407872);        // 0.5 MB
  half_t* v_wh  = (half_t*)(ws + 3932160);        // 0.5 MB
  half_t* U4    = (half_t*)(ws);                  // 20 MB (overlay)
  // Persistent region 20..26MB:
  half_t* pw_h = (half_t*)(ws + 20 * MB);           // 0.5 MB
  half_t* q_h  = (half_t*)(ws + 20 * MB + 524288);  // 2 MB
  half_t* k_h  = (half_t*)(ws + 22 * MB + 524288);  // 1.25 MB
  half_t* vT   = (half_t*)(ws + 24 * MB);           // 2 MB

  cvt_all<<<dim3(2432), 256, 0, stream>>>(x, anchors, qk_w, v_w, proj_w,
                                          x_h, anc_h, qk_h, v_wh, pw_h);

  proj_all<<<dim3(84, 8), 256, 0, stream>>>(x_h, anc_h, qk_h, v_wh, q_h, k_h, vT);

  const size_t lds_bytes = 16384 + 16384 + 8192 + 1024;  // 41,984 B
  fused_attn10<<<dim3(BB * NC * NH * 2), 512, lds_bytes, stream>>>(q_h, k_h, vT, weights,
                                                                   a0_out, U4);

  out_projA<<<dim3(64), 256, 0, stream>>>(U4, pw_h, proj_b, out0);

  (void)in_sizes; (void)n_in; (void)out_size; (void)ws_size;
}

// Round 13
// 143.656 us; speedup vs baseline: 1.1488x; 1.0414x over previous
//
#include <hip/hip_runtime.h>
#include <hip/hip_fp16.h>
#include <cstdint>

// Problem constants
#define BB 8
#define NN 256
#define NC 5
#define NH 8
#define DIM 512
#define HD 64

typedef _Float16 half_t;
typedef _Float16 h8 __attribute__((ext_vector_type(8)));
typedef _Float16 h4 __attribute__((ext_vector_type(4)));
typedef float f4 __attribute__((ext_vector_type(4)));
typedef uint32_t u4v __attribute__((ext_vector_type(4)));

__device__ __forceinline__ f4 mfma16(h8 a, h8 b, f4 c) {
  return __builtin_amdgcn_mfma_f32_16x16x32_f16(a, b, c, 0, 0, 0);
}

static __device__ const h8 HZERO = {(_Float16)0, (_Float16)0, (_Float16)0, (_Float16)0,
                                    (_Float16)0, (_Float16)0, (_Float16)0, (_Float16)0};

__device__ __forceinline__ h8 relu_pos_h8(h8 x) {
#if __has_builtin(__builtin_elementwise_max)
  return __builtin_elementwise_max(x, HZERO);
#else
  u4v u = __builtin_bit_cast(u4v, x);
  const u4v k1 = {0x00010001u, 0x00010001u, 0x00010001u, 0x00010001u};
  u4v s = (u >> 15) & k1;
  u4v m = (s << 16) - s;
  u = u & ~m;
  return __builtin_bit_cast(h8, u);
#endif
}

__device__ __forceinline__ h8 relu_neg_h8(h8 x) {
#if __has_builtin(__builtin_elementwise_max)
  return __builtin_elementwise_max(-x, HZERO);
#else
  u4v u = __builtin_bit_cast(u4v, x);
  const u4v k1 = {0x00010001u, 0x00010001u, 0x00010001u, 0x00010001u};
  const u4v ks = {0x80008000u, 0x80008000u, 0x80008000u, 0x80008000u};
  u4v s = (u >> 15) & k1;
  u4v m = (s << 16) - s;
  u = (u ^ ks) & m;
  return __builtin_bit_cast(h8, u);
#endif
}

// Raw barrier: waits LDS only, does NOT drain vmcnt (global stores stay in flight).
__device__ __forceinline__ void barrier_lds() {
  __builtin_amdgcn_sched_barrier(0);
  asm volatile("s_waitcnt lgkmcnt(0)" ::: "memory");
  __builtin_amdgcn_s_barrier();
  asm volatile("" ::: "memory");
  __builtin_amdgcn_sched_barrier(0);
}

// ---------------------------------------------------------------------------
// K0: convert x, anchors, qk_w, v_w, proj_w to fp16 (one f4->h4 per thread).
// ---------------------------------------------------------------------------
__global__ __launch_bounds__(256) void cvt_all(const float* __restrict__ x,
                                               const float* __restrict__ anchors,
                                               const float* __restrict__ qk_w,
                                               const float* __restrict__ v_w,
                                               const float* __restrict__ proj_w,
                                               half_t* __restrict__ x_h,
                                               half_t* __restrict__ anc_h,
                                               half_t* __restrict__ qk_h,
                                               half_t* __restrict__ v_wh,
                                               half_t* __restrict__ pw_h) {
  int i = blockIdx.x * 256 + threadIdx.x;
  const float* src;
  half_t* dst;
  int off;
  if (i < 262144)      { src = x;       dst = x_h;   off = i; }
  else if (i < 425984) { src = anchors; dst = anc_h; off = i - 262144; }
  else if (i < 491520) { src = qk_w;    dst = qk_h;  off = i - 425984; }
  else if (i < 557056) { src = v_w;     dst = v_wh;  off = i - 491520; }
  else                 { src = proj_w;  dst = pw_h;  off = i - 557056; }
  float4 v = ((const float4*)src)[off];
  h4 o;
  o[0] = (_Float16)v.x; o[1] = (_Float16)v.y; o[2] = (_Float16)v.z; o[3] = (_Float16)v.w;
  ((h4*)dst)[off] = o;
}

// ---------------------------------------------------------------------------
// K1: all three projections (pure fp16 operands).
//   bx <  32: q  = x_h @ qk_h^T   -> q_h [2048][512]
//   bx <  52: k  = anc_h @ qk_h^T -> k_h [1280][512]
//   else    : vT = (x_h @ v_wh^T)^T -> vT [512][2048]  ([h*64+d][b*256+m])
// ---------------------------------------------------------------------------
__global__ __launch_bounds__(256) void proj_all(const half_t* __restrict__ x_h,
                                                const half_t* __restrict__ anc_h,
                                                const half_t* __restrict__ qk_h,
                                                const half_t* __restrict__ v_wh,
                                                half_t* __restrict__ q_h,
                                                half_t* __restrict__ k_h,
                                                half_t* __restrict__ vT) {
  const int bx = blockIdx.x, by = blockIdx.y;
  const int tid = threadIdx.x;
  const int w = tid >> 6, lane = tid & 63;
  const int lr = lane & 15, lk = (lane >> 4) * 8, lg = lane >> 4;

  const half_t* A;
  const half_t* W;
  int mode, rt0;
  if (bx < 32)      { A = x_h;   W = qk_h; mode = 0; rt0 = bx * 64; }
  else if (bx < 52) { A = anc_h; W = qk_h; mode = 1; rt0 = (bx - 32) * 64; }
  else              { A = x_h;   W = v_wh; mode = 2; rt0 = (bx - 52) * 64; }

  const int row0 = rt0 + w * 16;
  const int col0 = by * 64;
  const f4 fz = {0.f, 0.f, 0.f, 0.f};
  f4 acc[4] = {fz, fz, fz, fz};
  const half_t* arow = A + (size_t)(row0 + lr) * DIM;

  if (mode != 2) {
    for (int k0 = 0; k0 < DIM; k0 += 32) {
      h8 a = *(const h8*)(arow + k0 + lk);
#pragma unroll
      for (int ct = 0; ct < 4; ++ct) {
        h8 b = *(const h8*)(W + (size_t)(col0 + ct * 16 + lr) * DIM + k0 + lk);
        acc[ct] = mfma16(a, b, acc[ct]);
      }
    }
    half_t* out = (mode == 0) ? q_h : k_h;
#pragma unroll
    for (int ct = 0; ct < 4; ++ct) {
      int col = col0 + ct * 16 + lr;
#pragma unroll
      for (int r = 0; r < 4; ++r) {
        int row = row0 + lg * 4 + r;
        out[(size_t)row * DIM + col] = (half_t)acc[ct][r];
      }
    }
  } else {
    for (int k0 = 0; k0 < DIM; k0 += 32) {
      h8 a = *(const h8*)(arow + k0 + lk);
#pragma unroll
      for (int ct = 0; ct < 4; ++ct) {
        h8 b = *(const h8*)(W + (size_t)(col0 + ct * 16 + lr) * DIM + k0 + lk);
        acc[ct] = mfma16(b, a, acc[ct]);
      }
    }
    const int xrow = row0 + lr;
#pragma unroll
    for (int ct = 0; ct < 4; ++ct) {
#pragma unroll
      for (int r = 0; r < 4; ++r) {
        int col = col0 + ct * 16 + lg * 4 + r;  // = h*64 + d
        vT[(size_t)col * (BB * NN) + xrow] = (half_t)acc[ct][r];
      }
    }
  }
}

// ---------------------------------------------------------------------------
// K2 (round-8 champion, verbatim): 2 half-blocks per (b,c,h), 1024 thr.
// ---------------------------------------------------------------------------
__global__ __launch_bounds__(1024, 4) void fused_attn5(const half_t* __restrict__ q_h,
                                                       const half_t* __restrict__ k_h,
                                                       const half_t* __restrict__ vT,
                                                       const float* __restrict__ weights,
                                                       float* __restrict__ a0_base,
                                                       half_t* __restrict__ U4) {
  extern __shared__ char smem[];
  half_t* a0s = (half_t*)smem;                        // [128][256] swz, 65536 B
  half_t* kst = (half_t*)(smem + 65536);              // [256][64] swz, 32768 B
  half_t* vst = kst;                                  // reuse: [64][128] swz, 16384 B
  half_t* wbuf = (half_t*)(smem + 98304);             // 16 waves x 640 h
  float2* scr = (float2*)(smem + 118784);             // [16 w][128 m'] f2, 16384 B
  float2* scr2 = (float2*)(smem + 135168);            // [128 m'] f2 (gm, sg), 1024 B

  const int id = blockIdx.x;          // 640 = 8*5*8*2
  const int b = id / 80;
  const int rem = id % 80;
  const int c = rem / 16;
  const int h = (rem >> 1) & 7;
  const int q = rem & 1;

  const int tid = threadIdx.x;
  const int w = tid >> 6, lane = tid & 63;
  const int lr = lane & 15, lk = (lane >> 4) * 8, lg = lane >> 4;
  const int n0 = w * 16;

  const half_t* qb = q_h + (size_t)(b * NN) * DIM + h * HD;
  const half_t* kb = k_h + (size_t)(c * NN) * DIM + h * HD;
  const half_t* vTb = vT + (size_t)(h * HD) * (BB * NN) + b * NN;
  float* a0out = a0_base + (size_t)((b * NC + c) * NH + h) * (NN * NN);
  const float wgt = weights[(b * NH + h) * NC + c];

  const f4 fz = {0.f, 0.f, 0.f, 0.f};

  // q fragments for this wave's 16 rows
  h8 qf0 = *(const h8*)(qb + (size_t)(n0 + lr) * DIM + lk);
  h8 qf1 = *(const h8*)(qb + (size_t)(n0 + lr) * DIM + 32 + lk);

  // ---- stage k tile [256][64] fp16, swizzled ----
#pragma unroll
  for (int pass = 0; pass < 2; ++pass) {
    int slot = pass * 1024 + tid;
    int row = slot >> 3, k8 = (slot & 7) * 8;
    h8 val = *(const h8*)(kb + (size_t)row * DIM + k8);
    *(h8*)(kst + ((row * 64 + k8) ^ ((row & 7) << 3))) = val;
  }
  barrier_lds();  // A

  // ---- phase 1: full a0 for L; half rows -> global fp32 + LDS fp16 ----
  half_t* Lb = wbuf + w * 640;  // [16][40]
  h8 La[8];
  const bool myhalf = ((w >> 3) == q);
  const int rl = (w & 7) * 16 + lr;  // local a0s row when myhalf
#pragma unroll
  for (int mt = 0; mt < 16; ++mt) {
    const int krow = mt * 16 + lr;
    h8 kf0 = *(const h8*)(kst + ((krow * 64 + lk) ^ ((krow & 7) << 3)));
    h8 kf1 = *(const h8*)(kst + ((krow * 64 + 32 + lk) ^ ((krow & 7) << 3)));
    f4 acc = mfma16(kf0, qf0, fz);
    acc = mfma16(kf1, qf1, acc);
    f4 v0;
    h4 hv;
#pragma unroll
    for (int r = 0; r < 4; ++r) {
      v0[r] = acc[r] * 0.125f;
      hv[r] = (_Float16)v0[r];
    }
    *(h4*)(Lb + lr * 40 + (mt & 1) * 16 + lg * 4) = hv;
    if (myhalf) {
      *(f4*)(a0out + (size_t)(n0 + lr) * NN + mt * 16 + lg * 4) = v0;
      *(h4*)(a0s + ((rl * 256 + mt * 16 + lg * 4) ^ ((rl & 7) << 3))) = hv;
    }
    if (mt & 1) {
      h8 raw = *(const h8*)(Lb + lr * 40 + lg * 8);
      La[mt >> 1] = relu_neg_h8(raw);
    }
  }
  barrier_lds();  // B (a0s ready; kst reads done)

  // ---- stage vT half-tile [64 d][128 m'] into dead kst region ----
  {
    int d = tid >> 4, m8 = (tid & 15) * 8;
    h8 val = *(const h8*)(vTb + (size_t)d * (BB * NN) + q * 128 + m8);
    *(h8*)(vst + ((d * 128 + m8) ^ ((d & 7) << 4))) = val;
  }

  // ---- S = L @ R^T over this block's 128 m' columns ----
  f4 sacc[8];
#pragma unroll
  for (int ct = 0; ct < 8; ++ct) sacc[ct] = fz;
#pragma unroll
  for (int kc = 0; kc < 8; ++kc) {
#pragma unroll
    for (int ct = 0; ct < 8; ++ct) {
      const int rr = ct * 16 + lr;
      h8 R = relu_pos_h8(*(const h8*)(a0s + ((rr * 256 + kc * 32 + lk) ^ ((rr & 7) << 3))));
      sacc[ct] = mfma16(La[kc], R, sacc[ct]);
    }
  }

  // ---- per-wave (max, sum) per column; exp in place ----
  float mw[8];
#pragma unroll
  for (int ct = 0; ct < 8; ++ct) {
    float v = 0.f;  // S >= 0 always
#pragma unroll
    for (int r = 0; r < 4; ++r) v = fmaxf(v, sacc[ct][r]);
    v = fmaxf(v, __shfl_xor(v, 16, 64));
    v = fmaxf(v, __shfl_xor(v, 32, 64));
    mw[ct] = v;
    float s = 0.f;
#pragma unroll
    for (int r = 0; r < 4; ++r) {
      float e = __expf(sacc[ct][r] - v);
      sacc[ct][r] = e;
      s += e;
    }
    s += __shfl_xor(s, 16, 64);
    s += __shfl_xor(s, 32, 64);
    if (lane < 16) {
      float2 t;
      t.x = v;
      t.y = s;
      scr[w * 128 + ct * 16 + lr] = t;
    }
  }
  barrier_lds();  // C

  // ---- combine across 16 waves: 128 threads, one column each ----
  if (tid < 128) {
    float gm = 0.f;
#pragma unroll
    for (int ww = 0; ww < 16; ++ww) gm = fmaxf(gm, scr[ww * 128 + tid].x);
    float sg = 0.f;
#pragma unroll
    for (int ww = 0; ww < 16; ++ww) {
      float2 t = scr[ww * 128 + tid];
      sg += t.y * __expf(t.x - gm);
    }
    float2 r;
    r.x = gm;
    r.y = sg;
    scr2[tid] = r;
  }
  barrier_lds();  // D

  float fac[8];
#pragma unroll
  for (int ct = 0; ct < 8; ++ct) {
    float2 t = scr2[ct * 16 + lr];
    fac[ct] = __expf(mw[ct] - t.x) * wgt / t.y;
  }

  // ---- PV: per 32-col panel, transpose-bounce P then MFMA with vst ----
  half_t* pbw = wbuf + w * 640;  // [32][20]
  f4 uacc[4] = {fz, fz, fz, fz};
#pragma unroll
  for (int pan = 0; pan < 4; ++pan) {
#pragma unroll
    for (int ctl = 0; ctl < 2; ++ctl) {
      const int ct = pan * 2 + ctl;
      h4 hv;
#pragma unroll
      for (int r = 0; r < 4; ++r) hv[r] = (_Float16)(sacc[ct][r] * fac[ct]);
      *(h4*)(pbw + (ctl * 16 + lr) * 20 + lg * 4) = hv;
    }
    h8 pf;
#pragma unroll
    for (int e = 0; e < 8; ++e) pf[e] = pbw[(lg * 8 + e) * 20 + lr];
#pragma unroll
    for (int dt = 0; dt < 4; ++dt) {
      const int dr = dt * 16 + lr;
      h8 vf = *(const h8*)(vst + ((dr * 128 + pan * 32 + lk) ^ ((dr & 7) << 4)));
      uacc[dt] = mfma16(vf, pf, uacc[dt]);
    }
  }

  // ---- store partial U4 (fp16): [n][d] ----
  half_t* U4b = U4 + (size_t)(((b * NC + c) * NH + h) * 2 + q) * (NN * HD);
#pragma unroll
  for (int dt = 0; dt < 4; ++dt) {
    h4 hv;
#pragma unroll
    for (int r = 0; r < 4; ++r) hv[r] = (_Float16)uacc[dt][r];
    *(h4*)(U4b + (size_t)(n0 + lr) * HD + dt * 16 + lg * 4) = hv;
  }
}

// ---------------------------------------------------------------------------
// K3: merged reduce + out-projection. 64 blocks, one per (b, hh) = 32 rows.
// Stage reduced A-tile (sum of 10 U4 partials) in LDS, then GEMM + bias.
// (Verified correct vs this exact U4 layout in rounds 6/10/12.)
// ---------------------------------------------------------------------------
__global__ __launch_bounds__(256) void out_projA(const half_t* __restrict__ U4,
                                                 const half_t* __restrict__ pw_h,
                                                 const float* __restrict__ pb,
                                                 float* __restrict__ out0) {
  __shared__ half_t Ast[32 * 520];  // [32 rows][512 k + 8 pad]
  const int bid = blockIdx.x;       // 64
  const int b = bid >> 3, hh = bid & 7;
  const int tid = threadIdx.x;

  // stage: thread (il = tid>>3, kk = tid&7) reduces 10 partial slices
  {
    const int il = tid >> 3, kk = tid & 7;
    const int n = (il << 3) | kk;
    const half_t* base = U4 + ((size_t)(b * NC * NH + hh) * 2) * (NN * HD) + (size_t)n * HD;
#pragma unroll
    for (int d0 = 0; d0 < HD; d0 += 8) {
      float a8[8] = {0.f, 0.f, 0.f, 0.f, 0.f, 0.f, 0.f, 0.f};
#pragma unroll
      for (int cc = 0; cc < NC; ++cc)
#pragma unroll
        for (int qq = 0; qq < 2; ++qq) {
          h8 u = *(const h8*)(base + (size_t)(cc * NH * 2 + qq) * (NN * HD) + d0);
#pragma unroll
          for (int j = 0; j < 8; ++j) a8[j] += (float)u[j];
        }
      h8 o;
#pragma unroll
      for (int j = 0; j < 8; ++j) o[j] = (_Float16)a8[j];
      *(h8*)(&Ast[il * 520 + kk * 64 + d0]) = o;
    }
  }
  __syncthreads();

  // GEMM: 4 waves x 128 cols each, 32 rows
  const int w = tid >> 6, lane = tid & 63;
  const int lr = lane & 15, lk = (lane >> 4) * 8, lg = lane >> 4;
  const int col0 = w * 128;
  const f4 fz = {0.f, 0.f, 0.f, 0.f};
  f4 acc[2][8];
#pragma unroll
  for (int rt = 0; rt < 2; ++rt)
#pragma unroll
    for (int ct = 0; ct < 8; ++ct) acc[rt][ct] = fz;

  for (int kc = 0; kc < 16; ++kc) {
    h8 a0f = *(const h8*)(&Ast[(lr)*520 + kc * 32 + lk]);
    h8 a1f = *(const h8*)(&Ast[(16 + lr) * 520 + kc * 32 + lk]);
#pragma unroll
    for (int ct = 0; ct < 8; ++ct) {
      h8 bf = *(const h8*)(pw_h + (size_t)(col0 + ct * 16 + lr) * DIM + kc * 32 + lk);
      acc[0][ct] = mfma16(a0f, bf, acc[0][ct]);
      acc[1][ct] = mfma16(a1f, bf, acc[1][ct]);
    }
  }

  const int row_base = b * NN + hh * 32;
#pragma unroll
  for (int ct = 0; ct < 8; ++ct) {
    int col = col0 + ct * 16 + lr;
    float bias = pb[col];
#pragma unroll
    for (int rt = 0; rt < 2; ++rt)
#pragma unroll
      for (int r = 0; r < 4; ++r) {
        int row = row_base + rt * 16 + lg * 4 + r;
        out0[(size_t)row * DIM + col] = acc[rt][ct][r] + bias;
      }
  }
}

// ---------------------------------------------------------------------------
extern "C" void kernel_launch(void* const* d_in, const int* in_sizes, int n_in,
                              void* d_out, int out_size, void* d_ws, size_t ws_size,
                              hipStream_t stream) {
  const float* x = (const float*)d_in[0];
  const float* anchors = (const float*)d_in[1];
  const float* weights = (const float*)d_in[2];
  const float* qk_w = (const float*)d_in[3];
  const float* v_w = (const float*)d_in[4];
  const float* proj_w = (const float*)d_in[5];
  const float* proj_b = (const float*)d_in[6];

  float* out0 = (float*)d_out;                       // [8,256,512]
  float* a0_out = out0 + (size_t)BB * NN * DIM;      // [8,5,8,256,256]

  char* ws = (char*)d_ws;
  const size_t MB = 1024 * 1024;
  // Region 0..20MB: fp16 staging (dead before fused_attn5) then U4 overlay.
  half_t* x_h   = (half_t*)(ws);                  // 2 MB
  half_t* anc_h = (half_t*)(ws + 2 * MB);         // 1.25 MB
  half_t* qk_h  = (half_t*)(ws + 3407872);        // 0.5 MB
  half_t* v_wh  = (half_t*)(ws + 3932160);        // 0.5 MB
  half_t* U4    = (half_t*)(ws);                  // 20 MB (overlay)
  // Persistent region 20..26MB:
  half_t* pw_h = (half_t*)(ws + 20 * MB);           // 0.5 MB
  half_t* q_h  = (half_t*)(ws + 20 * MB + 524288);  // 2 MB
  half_t* k_h  = (half_t*)(ws + 22 * MB + 524288);  // 1.25 MB
  half_t* vT   = (half_t*)(ws + 24 * MB);           // 2 MB

  cvt_all<<<dim3(2432), 256, 0, stream>>>(x, anchors, qk_w, v_w, proj_w,
                                          x_h, anc_h, qk_h, v_wh, pw_h);

  proj_all<<<dim3(84, 8), 256, 0, stream>>>(x_h, anc_h, qk_h, v_wh, q_h, k_h, vT);

  const size_t lds5 = 65536 + 32768 + 20480 + 16384 + 1024;  // 136,192 B
  fused_attn5<<<dim3(BB * NC * NH * 2), 1024, lds5, stream>>>(q_h, k_h, vT, weights,
                                                              a0_out, U4);

  out_projA<<<dim3(64), 256, 0, stream>>>(U4, pw_h, proj_b, out0);

  (void)in_sizes; (void)n_in; (void)out_size; (void)ws_size;
}